// Round 1
// baseline (1566.394 us; speedup 1.0000x reference)
//
#include <hip/hip_runtime.h>
#include <math.h>

#define S_LEN 2048
#define DM 1024
#define NH 16
#define DK 64

// ---------------------------------------------------------------------------
// RoPE cos/sin table: tab[p][i] = {cos(p*invf_i), sin(p*invf_i)}, i in [0,32)
// invf computed in fp32 exactly like the reference (theta^(-2i/64)).
// ---------------------------------------------------------------------------
__global__ __launch_bounds__(256) void rope_table_kernel(float* __restrict__ tab) {
    int idx = blockIdx.x * 256 + threadIdx.x;
    if (idx >= S_LEN * 32) return;
    int p = idx >> 5, i = idx & 31;
    float invf = powf(10000.0f, -(float)(2 * i) / 64.0f);
    float ang = (float)p * invf;
    tab[idx * 2 + 0] = cosf(ang);
    tab[idx * 2 + 1] = sinf(ang);
}

// ---------------------------------------------------------------------------
// Tiled fp32 GEMM: C[m,n] = sum_k A[m,k] * W[n,k]  (+bias, +epilogue)
// 64x64 tile, BK=16, 256 threads, 4x4 microtile.
// MODE 0: QKV projection. blockIdx.z in {0,1,2} selects Wq/Wk/Wv.
//         Epilogue: +bias, RoPE (z<2), scatter to [b,h,s,dk] workspace.
// MODE 1: output projection. Epilogue: +bias, write [b,s,e] to d_out.
// ---------------------------------------------------------------------------
template <int MODE>
__global__ __launch_bounds__(256) void gemm_kernel(
    const float* __restrict__ A,
    const float* __restrict__ W0, const float* __restrict__ W1, const float* __restrict__ W2,
    const float* __restrict__ b0, const float* __restrict__ b1, const float* __restrict__ b2,
    const float* __restrict__ rope_tab, const int* __restrict__ tokpos,
    float* __restrict__ d0, float* __restrict__ d1, float* __restrict__ d2)
{
    const int m0 = blockIdx.x * 64;
    const int n0 = blockIdx.y * 64;
    const int which = (MODE == 0) ? blockIdx.z : 0;
    const float* W    = (which == 0) ? W0 : (which == 1) ? W1 : W2;
    const float* bias = (which == 0) ? b0 : (which == 1) ? b1 : b2;

    // [16][68]: row stride 272B (multiple of 16B -> float4-aligned reads)
    __shared__ float As[16][68];
    __shared__ float Bs[16][68];

    const int t = threadIdx.x;
    const int tx = t & 15;        // n micro-tile index
    const int ty = t >> 4;        // m micro-tile index
    const int lrow = t >> 2;      // 0..63 staging row
    const int lk4  = (t & 3) << 2; // 0,4,8,12 staging k offset

    float acc[4][4] = {{0.f}};

    const float* Aptr = A + (long)(m0 + lrow) * DM + lk4;
    const float* Wptr = W + (long)(n0 + lrow) * DM + lk4;

    for (int k0 = 0; k0 < DM; k0 += 16) {
        float4 av = *(const float4*)(Aptr + k0);
        float4 wv = *(const float4*)(Wptr + k0);
        __syncthreads();  // previous iteration's reads complete
        As[lk4 + 0][lrow] = av.x; As[lk4 + 1][lrow] = av.y;
        As[lk4 + 2][lrow] = av.z; As[lk4 + 3][lrow] = av.w;
        Bs[lk4 + 0][lrow] = wv.x; Bs[lk4 + 1][lrow] = wv.y;
        Bs[lk4 + 2][lrow] = wv.z; Bs[lk4 + 3][lrow] = wv.w;
        __syncthreads();
#pragma unroll
        for (int k = 0; k < 16; ++k) {
            float4 a4 = *(const float4*)&As[k][ty << 2];
            float4 b4 = *(const float4*)&Bs[k][tx << 2];
            float aa[4] = {a4.x, a4.y, a4.z, a4.w};
            float bb[4] = {b4.x, b4.y, b4.z, b4.w};
#pragma unroll
            for (int i = 0; i < 4; ++i)
#pragma unroll
                for (int j = 0; j < 4; ++j)
                    acc[i][j] = fmaf(aa[i], bb[j], acc[i][j]);
        }
    }

    const int e0 = n0 + (tx << 2);

    if (MODE == 1) {
        float4 bb4 = *(const float4*)(bias + e0);
#pragma unroll
        for (int i = 0; i < 4; ++i) {
            int m = m0 + (ty << 2) + i;
            float4 o;
            o.x = acc[i][0] + bb4.x;
            o.y = acc[i][1] + bb4.y;
            o.z = acc[i][2] + bb4.z;
            o.w = acc[i][3] + bb4.w;
            *(float4*)(d0 + (long)m * DM + e0) = o;
        }
    } else {
        const int h = e0 >> 6;
        const int dbase = e0 & 63;          // multiple of 4 (even)
        const int fi = dbase >> 1;          // freq index of first pair
        float* dst = (which == 0) ? d0 : (which == 1) ? d1 : d2;
        const float bias0 = bias[e0 + 0], bias1 = bias[e0 + 1];
        const float bias2 = bias[e0 + 2], bias3 = bias[e0 + 3];
#pragma unroll
        for (int i = 0; i < 4; ++i) {
            int m = m0 + (ty << 2) + i;
            int b_idx = m >> 11;
            int s_idx = m & (S_LEN - 1);
            long base = ((long)((b_idx * NH + h) * S_LEN + s_idx)) * DK + dbase;
            float c0 = acc[i][0] + bias0, c1 = acc[i][1] + bias1;
            float c2 = acc[i][2] + bias2, c3 = acc[i][3] + bias3;
            if (which == 2) {   // V: no RoPE
                dst[base + 0] = c0; dst[base + 1] = c1;
                dst[base + 2] = c2; dst[base + 3] = c3;
            } else {
                int pos = tokpos[m];
                float2 cs0 = ((const float2*)rope_tab)[pos * 32 + fi];
                float2 cs1 = ((const float2*)rope_tab)[pos * 32 + fi + 1];
                dst[base + 0] = c0 * cs0.x - c1 * cs0.y;
                dst[base + 1] = c0 * cs0.y + c1 * cs0.x;
                dst[base + 2] = c2 * cs1.x - c3 * cs1.y;
                dst[base + 3] = c2 * cs1.y + c3 * cs1.x;
            }
        }
    }
}

// ---------------------------------------------------------------------------
// fp32 flash attention, causal. Grid (s/256, b*h). 256 threads; thread t owns
// q-row r0+t (q and o accumulator in registers). K/V staged in 64-row LDS
// tiles; all lanes read the same K/V row -> LDS broadcast, conflict-free.
// Online softmax over 16-column subtiles (sc[16] stays statically indexed).
// ---------------------------------------------------------------------------
__global__ __launch_bounds__(256, 1) void flash_kernel(
    const float* __restrict__ q_ws, const float* __restrict__ k_ws,
    const float* __restrict__ v_ws, float* __restrict__ attn_ws)
{
    const int bh = blockIdx.y;
    const int r0 = blockIdx.x * 256;
    const int t = threadIdx.x;
    const int row = r0 + t;
    const int h = bh & (NH - 1);
    const int b_idx = bh >> 4;

    __shared__ float Ks[64][64];
    __shared__ float Vs[64][64];

    const float* qp = q_ws + ((long)bh * S_LEN + row) * DK;
    float4 q4[16];
#pragma unroll
    for (int i = 0; i < 16; ++i) q4[i] = *(const float4*)(qp + i * 4);

    float4 o4[16];
#pragma unroll
    for (int i = 0; i < 16; ++i) o4[i] = make_float4(0.f, 0.f, 0.f, 0.f);
    float mrun = -INFINITY, lrun = 0.0f;

    const int wave_row_max = row | 63;   // rows contiguous per wave
    const int ntile = (r0 + 256) >> 6;
    const int srow = t >> 4;             // 0..15
    const int scol = (t & 15) << 2;      // 0..60

    for (int tile = 0; tile < ntile; ++tile) {
        const int j0 = tile << 6;
        __syncthreads();
#pragma unroll
        for (int i = 0; i < 4; ++i) {
            int r = srow + (i << 4);
            const long kbase = ((long)bh * S_LEN + j0 + r) * DK + scol;
            *(float4*)&Ks[r][scol] = *(const float4*)(k_ws + kbase);
            *(float4*)&Vs[r][scol] = *(const float4*)(v_ws + kbase);
        }
        __syncthreads();

        for (int sub = 0; sub < 4; ++sub) {
            const int jb = sub << 4;
            if (j0 + jb > wave_row_max) break;   // wave-uniform causal skip

            float sc[16];
            float tmax = -INFINITY;
#pragma unroll
            for (int j = 0; j < 16; ++j) {
                const int jj = jb + j;
                float4 a = make_float4(0.f, 0.f, 0.f, 0.f);
#pragma unroll
                for (int i = 0; i < 16; ++i) {
                    float4 kv = *(const float4*)&Ks[jj][i << 2];
                    a.x = fmaf(q4[i].x, kv.x, a.x);
                    a.y = fmaf(q4[i].y, kv.y, a.y);
                    a.z = fmaf(q4[i].z, kv.z, a.z);
                    a.w = fmaf(q4[i].w, kv.w, a.w);
                }
                float sv = ((a.x + a.y) + (a.z + a.w)) * 0.125f;
                sc[j] = (j0 + jj <= row) ? sv : -INFINITY;
                tmax = fmaxf(tmax, sc[j]);
            }

            float mnew = fmaxf(mrun, tmax);
            float corr = __expf(mrun - mnew);    // first subtile: exp(-inf)=0
            lrun *= corr;
#pragma unroll
            for (int i = 0; i < 16; ++i) {
                o4[i].x *= corr; o4[i].y *= corr;
                o4[i].z *= corr; o4[i].w *= corr;
            }
#pragma unroll
            for (int j = 0; j < 16; ++j) {
                float p = __expf(sc[j] - mnew);  // masked -> exp(-inf)=0
                lrun += p;
#pragma unroll
                for (int i = 0; i < 16; ++i) {
                    float4 vv = *(const float4*)&Vs[jb + j][i << 2];
                    o4[i].x = fmaf(p, vv.x, o4[i].x);
                    o4[i].y = fmaf(p, vv.y, o4[i].y);
                    o4[i].z = fmaf(p, vv.z, o4[i].z);
                    o4[i].w = fmaf(p, vv.w, o4[i].w);
                }
            }
            mrun = mnew;
        }
    }

    const float inv = 1.0f / lrun;
    float* op = attn_ws + ((long)(b_idx * S_LEN + row)) * DM + h * DK;
#pragma unroll
    for (int i = 0; i < 16; ++i) {
        float4 o = o4[i];
        o.x *= inv; o.y *= inv; o.z *= inv; o.w *= inv;
        *(float4*)(op + i * 4) = o;
    }
}

// ---------------------------------------------------------------------------
extern "C" void kernel_launch(void* const* d_in, const int* in_sizes, int n_in,
                              void* d_out, int out_size, void* d_ws, size_t ws_size,
                              hipStream_t stream) {
    const float* x   = (const float*)d_in[0];
    const float* Wq  = (const float*)d_in[1];
    const float* bq  = (const float*)d_in[2];
    const float* Wk  = (const float*)d_in[3];
    const float* bk  = (const float*)d_in[4];
    const float* Wv  = (const float*)d_in[5];
    const float* bv  = (const float*)d_in[6];
    const float* Wo  = (const float*)d_in[7];
    const float* bo  = (const float*)d_in[8];
    const int* tokpos = (const int*)d_in[9];
    float* out = (float*)d_out;

    float* ws = (float*)d_ws;
    const long Mel = 4096L * 1024;      // 4M floats = 16 MB each
    float* q_ws    = ws;                 // [b,h,s,dk]
    float* k_ws    = ws + Mel;           // [b,h,s,dk]
    float* v_ws    = ws + 2 * Mel;       // [b,h,s,dk]
    float* attn_ws = ws + 3 * Mel;       // [b,s,h*dk]
    float* rope_tab = ws + 4 * Mel;      // [2048][32][2] = 512 KB

    rope_table_kernel<<<(S_LEN * 32 + 255) / 256, 256, 0, stream>>>(rope_tab);

    // QKV projections + bias + RoPE + [b,h,s,dk] scatter
    gemm_kernel<0><<<dim3(64, 16, 3), 256, 0, stream>>>(
        x, Wq, Wk, Wv, bq, bk, bv, rope_tab, tokpos, q_ws, k_ws, v_ws);

    // causal flash attention
    flash_kernel<<<dim3(8, 32), 256, 0, stream>>>(q_ws, k_ws, v_ws, attn_ws);

    // output projection + bias -> d_out
    gemm_kernel<1><<<dim3(64, 16, 1), 256, 0, stream>>>(
        attn_ws, Wo, nullptr, nullptr, bo, nullptr, nullptr,
        nullptr, nullptr, out, nullptr, nullptr);
}

// Round 2
// 1102.896 us; speedup vs baseline: 1.4203x; 1.4203x over previous
//
#include <hip/hip_runtime.h>
#include <math.h>

#define S_LEN 2048
#define DM 1024
#define NH 16
#define DK 64

// ---------------------------------------------------------------------------
// RoPE cos/sin table: tab[p][i] = {cos(p*invf_i), sin(p*invf_i)}, i in [0,32)
// ---------------------------------------------------------------------------
__global__ __launch_bounds__(256) void rope_table_kernel(float* __restrict__ tab) {
    int idx = blockIdx.x * 256 + threadIdx.x;
    if (idx >= S_LEN * 32) return;
    int p = idx >> 5, i = idx & 31;
    float invf = powf(10000.0f, -(float)(2 * i) / 64.0f);
    float ang = (float)p * invf;
    tab[idx * 2 + 0] = cosf(ang);
    tab[idx * 2 + 1] = sinf(ang);
}

// ---------------------------------------------------------------------------
// Tiled fp32 GEMM: C[m,n] = sum_k A[m,k] * W[n,k]  (+bias, +epilogue)
// MODE 0: QKV projection (+RoPE, scatter [b,h,s,dk]).  MODE 1: out proj.
// ---------------------------------------------------------------------------
template <int MODE>
__global__ __launch_bounds__(256) void gemm_kernel(
    const float* __restrict__ A,
    const float* __restrict__ W0, const float* __restrict__ W1, const float* __restrict__ W2,
    const float* __restrict__ b0, const float* __restrict__ b1, const float* __restrict__ b2,
    const float* __restrict__ rope_tab, const int* __restrict__ tokpos,
    float* __restrict__ d0, float* __restrict__ d1, float* __restrict__ d2)
{
    const int m0 = blockIdx.x * 64;
    const int n0 = blockIdx.y * 64;
    const int which = (MODE == 0) ? blockIdx.z : 0;
    const float* W    = (which == 0) ? W0 : (which == 1) ? W1 : W2;
    const float* bias = (which == 0) ? b0 : (which == 1) ? b1 : b2;

    __shared__ float As[16][68];
    __shared__ float Bs[16][68];

    const int t = threadIdx.x;
    const int tx = t & 15;
    const int ty = t >> 4;
    const int lrow = t >> 2;
    const int lk4  = (t & 3) << 2;

    float acc[4][4] = {{0.f}};

    const float* Aptr = A + (long)(m0 + lrow) * DM + lk4;
    const float* Wptr = W + (long)(n0 + lrow) * DM + lk4;

    for (int k0 = 0; k0 < DM; k0 += 16) {
        float4 av = *(const float4*)(Aptr + k0);
        float4 wv = *(const float4*)(Wptr + k0);
        __syncthreads();
        As[lk4 + 0][lrow] = av.x; As[lk4 + 1][lrow] = av.y;
        As[lk4 + 2][lrow] = av.z; As[lk4 + 3][lrow] = av.w;
        Bs[lk4 + 0][lrow] = wv.x; Bs[lk4 + 1][lrow] = wv.y;
        Bs[lk4 + 2][lrow] = wv.z; Bs[lk4 + 3][lrow] = wv.w;
        __syncthreads();
#pragma unroll
        for (int k = 0; k < 16; ++k) {
            float4 a4 = *(const float4*)&As[k][ty << 2];
            float4 b4 = *(const float4*)&Bs[k][tx << 2];
            float aa[4] = {a4.x, a4.y, a4.z, a4.w};
            float bb[4] = {b4.x, b4.y, b4.z, b4.w};
#pragma unroll
            for (int i = 0; i < 4; ++i)
#pragma unroll
                for (int j = 0; j < 4; ++j)
                    acc[i][j] = fmaf(aa[i], bb[j], acc[i][j]);
        }
    }

    const int e0 = n0 + (tx << 2);

    if (MODE == 1) {
        float4 bb4 = *(const float4*)(bias + e0);
#pragma unroll
        for (int i = 0; i < 4; ++i) {
            int m = m0 + (ty << 2) + i;
            float4 o;
            o.x = acc[i][0] + bb4.x;
            o.y = acc[i][1] + bb4.y;
            o.z = acc[i][2] + bb4.z;
            o.w = acc[i][3] + bb4.w;
            *(float4*)(d0 + (long)m * DM + e0) = o;
        }
    } else {
        const int h = e0 >> 6;
        const int dbase = e0 & 63;
        const int fi = dbase >> 1;
        float* dst = (which == 0) ? d0 : (which == 1) ? d1 : d2;
        const float bias0 = bias[e0 + 0], bias1 = bias[e0 + 1];
        const float bias2 = bias[e0 + 2], bias3 = bias[e0 + 3];
#pragma unroll
        for (int i = 0; i < 4; ++i) {
            int m = m0 + (ty << 2) + i;
            int b_idx = m >> 11;
            int s_idx = m & (S_LEN - 1);
            long base = ((long)((b_idx * NH + h) * S_LEN + s_idx)) * DK + dbase;
            float c0 = acc[i][0] + bias0, c1 = acc[i][1] + bias1;
            float c2 = acc[i][2] + bias2, c3 = acc[i][3] + bias3;
            if (which == 2) {
                dst[base + 0] = c0; dst[base + 1] = c1;
                dst[base + 2] = c2; dst[base + 3] = c3;
            } else {
                int pos = tokpos[m];
                float2 cs0 = ((const float2*)rope_tab)[pos * 32 + fi];
                float2 cs1 = ((const float2*)rope_tab)[pos * 32 + fi + 1];
                dst[base + 0] = c0 * cs0.x - c1 * cs0.y;
                dst[base + 1] = c0 * cs0.y + c1 * cs0.x;
                dst[base + 2] = c2 * cs1.x - c3 * cs1.y;
                dst[base + 3] = c2 * cs1.y + c3 * cs1.x;
            }
        }
    }
}

// ---------------------------------------------------------------------------
// GEMM-style fp32 flash attention, causal.
// Grid (32 q-tiles [reversed for balance], 32 bh). 256 threads.
// 64x64 score tile per block, 4x4 microtile per thread (tx = kv cols,
// ty = q rows). Q staged transposed once; K staged transposed + V natural
// per kv-tile with register prefetch. P round-trips through LDS for the
// PV GEMM. Softmax row-state reduced across tx via shfl_xor(width 16).
// LDS = 4 * 64*68*4B = 68 KB -> 2 blocks/CU.
// ---------------------------------------------------------------------------
__global__ __launch_bounds__(256, 2) void flash_kernel(
    const float* __restrict__ q_ws, const float* __restrict__ k_ws,
    const float* __restrict__ v_ws, float* __restrict__ attn_ws)
{
    const int bh = blockIdx.y;
    const int qi = (int)(gridDim.x - 1) - (int)blockIdx.x;  // heavy tiles first
    const int t = threadIdx.x;
    const int tx = t & 15;
    const int ty = t >> 4;
    const int h = bh & (NH - 1);
    const int b_idx = bh >> 4;

    __shared__ float Qs[64][68];   // [d][qrow]
    __shared__ float Ks[64][68];   // [d][kvcol]
    __shared__ float Vs[64][68];   // [kv][d]
    __shared__ float Ps[64][68];   // [kv][qrow]

    const int lr   = t & 63;          // staging row
    const int dblk = (t >> 6) << 4;   // 0,16,32,48

    // ---- stage Q tile, transposed ----
    {
        const float* qp = q_ws + ((long)bh * S_LEN + qi * 64 + lr) * DK + dblk;
        float4 a0 = *(const float4*)(qp + 0);
        float4 a1 = *(const float4*)(qp + 4);
        float4 a2 = *(const float4*)(qp + 8);
        float4 a3 = *(const float4*)(qp + 12);
        Qs[dblk +  0][lr] = a0.x; Qs[dblk +  1][lr] = a0.y; Qs[dblk +  2][lr] = a0.z; Qs[dblk +  3][lr] = a0.w;
        Qs[dblk +  4][lr] = a1.x; Qs[dblk +  5][lr] = a1.y; Qs[dblk +  6][lr] = a1.z; Qs[dblk +  7][lr] = a1.w;
        Qs[dblk +  8][lr] = a2.x; Qs[dblk +  9][lr] = a2.y; Qs[dblk + 10][lr] = a2.z; Qs[dblk + 11][lr] = a2.w;
        Qs[dblk + 12][lr] = a3.x; Qs[dblk + 13][lr] = a3.y; Qs[dblk + 14][lr] = a3.z; Qs[dblk + 15][lr] = a3.w;
    }

    // ---- register prefetch of K/V tile 0 ----
    float4 kr0, kr1, kr2, kr3, vr0, vr1, vr2, vr3;
    {
        const long base = ((long)bh * S_LEN + 0 * 64 + lr) * DK + dblk;
        kr0 = *(const float4*)(k_ws + base + 0);
        kr1 = *(const float4*)(k_ws + base + 4);
        kr2 = *(const float4*)(k_ws + base + 8);
        kr3 = *(const float4*)(k_ws + base + 12);
        vr0 = *(const float4*)(v_ws + base + 0);
        vr1 = *(const float4*)(v_ws + base + 4);
        vr2 = *(const float4*)(v_ws + base + 8);
        vr3 = *(const float4*)(v_ws + base + 12);
    }

    float o[4][4] = {{0.f}};
    float m_[4] = {-INFINITY, -INFINITY, -INFINITY, -INFINITY};
    float l_[4] = {0.f, 0.f, 0.f, 0.f};

    const int ntiles = qi + 1;
    for (int tile = 0; tile < ntiles; ++tile) {
        __syncthreads();   // prev PV done reading Vs/Ps; Qs staged (tile 0)

        // commit prefetched K (transposed) and V (natural) to LDS
        Ks[dblk +  0][lr] = kr0.x; Ks[dblk +  1][lr] = kr0.y; Ks[dblk +  2][lr] = kr0.z; Ks[dblk +  3][lr] = kr0.w;
        Ks[dblk +  4][lr] = kr1.x; Ks[dblk +  5][lr] = kr1.y; Ks[dblk +  6][lr] = kr1.z; Ks[dblk +  7][lr] = kr1.w;
        Ks[dblk +  8][lr] = kr2.x; Ks[dblk +  9][lr] = kr2.y; Ks[dblk + 10][lr] = kr2.z; Ks[dblk + 11][lr] = kr2.w;
        Ks[dblk + 12][lr] = kr3.x; Ks[dblk + 13][lr] = kr3.y; Ks[dblk + 14][lr] = kr3.z; Ks[dblk + 15][lr] = kr3.w;
        *(float4*)&Vs[lr][dblk +  0] = vr0;
        *(float4*)&Vs[lr][dblk +  4] = vr1;
        *(float4*)&Vs[lr][dblk +  8] = vr2;
        *(float4*)&Vs[lr][dblk + 12] = vr3;
        __syncthreads();

        // issue prefetch for next tile (hidden under QK+softmax+PV)
        if (tile + 1 < ntiles) {
            const long base = ((long)bh * S_LEN + (tile + 1) * 64 + lr) * DK + dblk;
            kr0 = *(const float4*)(k_ws + base + 0);
            kr1 = *(const float4*)(k_ws + base + 4);
            kr2 = *(const float4*)(k_ws + base + 8);
            kr3 = *(const float4*)(k_ws + base + 12);
            vr0 = *(const float4*)(v_ws + base + 0);
            vr1 = *(const float4*)(v_ws + base + 4);
            vr2 = *(const float4*)(v_ws + base + 8);
            vr3 = *(const float4*)(v_ws + base + 12);
        }

        // ---- QK^T: 64x64 tile, 4x4 per thread ----
        float sc[4][4] = {{0.f}};
#pragma unroll 8
        for (int d = 0; d < 64; ++d) {
            float4 qa = *(const float4*)&Qs[d][ty << 2];
            float4 kb = *(const float4*)&Ks[d][tx << 2];
            float aa[4] = {qa.x, qa.y, qa.z, qa.w};
            float bb[4] = {kb.x, kb.y, kb.z, kb.w};
#pragma unroll
            for (int i = 0; i < 4; ++i)
#pragma unroll
                for (int j = 0; j < 4; ++j)
                    sc[i][j] = fmaf(aa[i], bb[j], sc[i][j]);
        }

        // ---- scale + causal mask (diagonal tile only) ----
        if (tile == qi) {
#pragma unroll
            for (int i = 0; i < 4; ++i)
#pragma unroll
                for (int j = 0; j < 4; ++j) {
                    float sv = sc[i][j] * 0.125f;
                    sc[i][j] = (((tx << 2) + j) > ((ty << 2) + i)) ? -INFINITY : sv;
                }
        } else {
#pragma unroll
            for (int i = 0; i < 4; ++i)
#pragma unroll
                for (int j = 0; j < 4; ++j)
                    sc[i][j] *= 0.125f;
        }

        // ---- online softmax ----
        float tmax[4], tsum[4];
#pragma unroll
        for (int i = 0; i < 4; ++i) {
            float v = fmaxf(fmaxf(sc[i][0], sc[i][1]), fmaxf(sc[i][2], sc[i][3]));
            v = fmaxf(v, __shfl_xor(v, 1, 16));
            v = fmaxf(v, __shfl_xor(v, 2, 16));
            v = fmaxf(v, __shfl_xor(v, 4, 16));
            v = fmaxf(v, __shfl_xor(v, 8, 16));
            tmax[i] = v;
        }
#pragma unroll
        for (int i = 0; i < 4; ++i) {
            float mnew = fmaxf(m_[i], tmax[i]);
            float corr = __expf(m_[i] - mnew);   // first tile: exp(-inf)=0
            float s0 = __expf(sc[i][0] - mnew);
            float s1 = __expf(sc[i][1] - mnew);
            float s2 = __expf(sc[i][2] - mnew);
            float s3 = __expf(sc[i][3] - mnew);
            sc[i][0] = s0; sc[i][1] = s1; sc[i][2] = s2; sc[i][3] = s3;
            float v = (s0 + s1) + (s2 + s3);
            v += __shfl_xor(v, 1, 16);
            v += __shfl_xor(v, 2, 16);
            v += __shfl_xor(v, 4, 16);
            v += __shfl_xor(v, 8, 16);
            tsum[i] = v;
            l_[i] = l_[i] * corr + tsum[i];
            m_[i] = mnew;
            o[i][0] *= corr; o[i][1] *= corr; o[i][2] *= corr; o[i][3] *= corr;
        }

        // ---- write P transposed: Ps[kvcol][qrow] ----
#pragma unroll
        for (int j = 0; j < 4; ++j) {
            float4 pj = make_float4(sc[0][j], sc[1][j], sc[2][j], sc[3][j]);
            *(float4*)&Ps[(tx << 2) + j][ty << 2] = pj;
        }
        __syncthreads();

        // ---- PV: o += P^T(64q x 64kv) * V(64kv x 64d) ----
#pragma unroll 8
        for (int kv = 0; kv < 64; ++kv) {
            float4 pa = *(const float4*)&Ps[kv][ty << 2];
            float4 vb = *(const float4*)&Vs[kv][tx << 2];
            float aa[4] = {pa.x, pa.y, pa.z, pa.w};
            float bb[4] = {vb.x, vb.y, vb.z, vb.w};
#pragma unroll
            for (int i = 0; i < 4; ++i)
#pragma unroll
                for (int j = 0; j < 4; ++j)
                    o[i][j] = fmaf(aa[i], bb[j], o[i][j]);
        }
    }

    // ---- epilogue: normalize, store to attn_ws[b][s][h*64+d] ----
#pragma unroll
    for (int i = 0; i < 4; ++i) {
        float inv = 1.0f / l_[i];
        int row = qi * 64 + (ty << 2) + i;
        float4 ov = make_float4(o[i][0] * inv, o[i][1] * inv, o[i][2] * inv, o[i][3] * inv);
        *(float4*)(attn_ws + ((long)(b_idx * S_LEN + row)) * DM + h * DK + (tx << 2)) = ov;
    }
}

// ---------------------------------------------------------------------------
extern "C" void kernel_launch(void* const* d_in, const int* in_sizes, int n_in,
                              void* d_out, int out_size, void* d_ws, size_t ws_size,
                              hipStream_t stream) {
    const float* x   = (const float*)d_in[0];
    const float* Wq  = (const float*)d_in[1];
    const float* bq  = (const float*)d_in[2];
    const float* Wk  = (const float*)d_in[3];
    const float* bk  = (const float*)d_in[4];
    const float* Wv  = (const float*)d_in[5];
    const float* bv  = (const float*)d_in[6];
    const float* Wo  = (const float*)d_in[7];
    const float* bo  = (const float*)d_in[8];
    const int* tokpos = (const int*)d_in[9];
    float* out = (float*)d_out;

    float* ws = (float*)d_ws;
    const long Mel = 4096L * 1024;      // 16 MB each
    float* q_ws    = ws;
    float* k_ws    = ws + Mel;
    float* v_ws    = ws + 2 * Mel;
    float* attn_ws = ws + 3 * Mel;
    float* rope_tab = ws + 4 * Mel;

    rope_table_kernel<<<(S_LEN * 32 + 255) / 256, 256, 0, stream>>>(rope_tab);

    gemm_kernel<0><<<dim3(64, 16, 3), 256, 0, stream>>>(
        x, Wq, Wk, Wv, bq, bk, bv, rope_tab, tokpos, q_ws, k_ws, v_ws);

    flash_kernel<<<dim3(32, 32), 256, 0, stream>>>(q_ws, k_ws, v_ws, attn_ws);

    gemm_kernel<1><<<dim3(64, 16, 1), 256, 0, stream>>>(
        attn_ws, Wo, nullptr, nullptr, bo, nullptr, nullptr,
        nullptr, nullptr, out, nullptr, nullptr);
}

// Round 3
// 844.594 us; speedup vs baseline: 1.8546x; 1.3058x over previous
//
#include <hip/hip_runtime.h>
#include <math.h>

#define S_LEN 2048
#define DM 1024
#define NH 16
#define DK 64

typedef short s8v __attribute__((ext_vector_type(8)));   // 8 bf16 (A/B frag, 4 VGPR)
typedef float f4v __attribute__((ext_vector_type(4)));   // 4 f32  (C/D frag)

__device__ inline ushort bf16_rn(float v) {
    unsigned u = __float_as_uint(v);
    u += 0x7FFFu + ((u >> 16) & 1u);
    return (ushort)(u >> 16);
}
__device__ inline float bf16f(ushort h) { return __uint_as_float(((unsigned)h) << 16); }

// ---------------------------------------------------------------------------
// RoPE cos/sin table: tab[p][i] = {cos(p*invf_i), sin(p*invf_i)}, i in [0,32)
// ---------------------------------------------------------------------------
__global__ __launch_bounds__(256) void rope_table_kernel(float* __restrict__ tab) {
    int idx = blockIdx.x * 256 + threadIdx.x;
    if (idx >= S_LEN * 32) return;
    int p = idx >> 5, i = idx & 31;
    float invf = powf(10000.0f, -(float)(2 * i) / 64.0f);
    float ang = (float)p * invf;
    tab[idx * 2 + 0] = cosf(ang);
    tab[idx * 2 + 1] = sinf(ang);
}

// ---------------------------------------------------------------------------
// Tiled fp32 GEMM: C[m,n] = sum_k A[m,k] * W[n,k]  (+bias, +epilogue)
// MODE 0: QKV proj (+RoPE), writes bf16 hi/lo split arrays [b,h,s,dk].
// MODE 1: out proj, writes fp32 d_out.
// ---------------------------------------------------------------------------
template <int MODE>
__global__ __launch_bounds__(256) void gemm_kernel(
    const float* __restrict__ A,
    const float* __restrict__ W0, const float* __restrict__ W1, const float* __restrict__ W2,
    const float* __restrict__ b0, const float* __restrict__ b1, const float* __restrict__ b2,
    const float* __restrict__ rope_tab, const int* __restrict__ tokpos,
    ushort* __restrict__ qh, ushort* __restrict__ ql,
    ushort* __restrict__ kh, ushort* __restrict__ kl,
    ushort* __restrict__ vh, ushort* __restrict__ vl,
    float* __restrict__ out)
{
    const int m0 = blockIdx.x * 64;
    const int n0 = blockIdx.y * 64;
    const int which = (MODE == 0) ? blockIdx.z : 0;
    const float* W    = (which == 0) ? W0 : (which == 1) ? W1 : W2;
    const float* bias = (which == 0) ? b0 : (which == 1) ? b1 : b2;

    __shared__ float As[16][68];
    __shared__ float Bs[16][68];

    const int t = threadIdx.x;
    const int tx = t & 15;
    const int ty = t >> 4;
    const int lrow = t >> 2;
    const int lk4  = (t & 3) << 2;

    float acc[4][4] = {{0.f}};

    const float* Aptr = A + (long)(m0 + lrow) * DM + lk4;
    const float* Wptr = W + (long)(n0 + lrow) * DM + lk4;

    for (int k0 = 0; k0 < DM; k0 += 16) {
        float4 av = *(const float4*)(Aptr + k0);
        float4 wv = *(const float4*)(Wptr + k0);
        __syncthreads();
        As[lk4 + 0][lrow] = av.x; As[lk4 + 1][lrow] = av.y;
        As[lk4 + 2][lrow] = av.z; As[lk4 + 3][lrow] = av.w;
        Bs[lk4 + 0][lrow] = wv.x; Bs[lk4 + 1][lrow] = wv.y;
        Bs[lk4 + 2][lrow] = wv.z; Bs[lk4 + 3][lrow] = wv.w;
        __syncthreads();
#pragma unroll
        for (int k = 0; k < 16; ++k) {
            float4 a4 = *(const float4*)&As[k][ty << 2];
            float4 b4 = *(const float4*)&Bs[k][tx << 2];
            float aa[4] = {a4.x, a4.y, a4.z, a4.w};
            float bb[4] = {b4.x, b4.y, b4.z, b4.w};
#pragma unroll
            for (int i = 0; i < 4; ++i)
#pragma unroll
                for (int j = 0; j < 4; ++j)
                    acc[i][j] = fmaf(aa[i], bb[j], acc[i][j]);
        }
    }

    const int e0 = n0 + (tx << 2);

    if (MODE == 1) {
        float4 bb4 = *(const float4*)(bias + e0);
#pragma unroll
        for (int i = 0; i < 4; ++i) {
            int m = m0 + (ty << 2) + i;
            float4 o;
            o.x = acc[i][0] + bb4.x;
            o.y = acc[i][1] + bb4.y;
            o.z = acc[i][2] + bb4.z;
            o.w = acc[i][3] + bb4.w;
            *(float4*)(out + (long)m * DM + e0) = o;
        }
    } else {
        const int h = e0 >> 6;
        const int dbase = e0 & 63;
        const int fi = dbase >> 1;
        ushort* dh = (which == 0) ? qh : (which == 1) ? kh : vh;
        ushort* dl = (which == 0) ? ql : (which == 1) ? kl : vl;
        const float bias0 = bias[e0 + 0], bias1 = bias[e0 + 1];
        const float bias2 = bias[e0 + 2], bias3 = bias[e0 + 3];
#pragma unroll
        for (int i = 0; i < 4; ++i) {
            int m = m0 + (ty << 2) + i;
            int b_idx = m >> 11;
            int s_idx = m & (S_LEN - 1);
            long base = ((long)((b_idx * NH + h) * S_LEN + s_idx)) * DK + dbase;
            float c0 = acc[i][0] + bias0, c1 = acc[i][1] + bias1;
            float c2 = acc[i][2] + bias2, c3 = acc[i][3] + bias3;
            float r0, r1, r2, r3;
            if (which == 2) {
                r0 = c0; r1 = c1; r2 = c2; r3 = c3;
            } else {
                int pos = tokpos[m];
                float2 cs0 = ((const float2*)rope_tab)[pos * 32 + fi];
                float2 cs1 = ((const float2*)rope_tab)[pos * 32 + fi + 1];
                r0 = c0 * cs0.x - c1 * cs0.y;
                r1 = c0 * cs0.y + c1 * cs0.x;
                r2 = c2 * cs1.x - c3 * cs1.y;
                r3 = c2 * cs1.y + c3 * cs1.x;
            }
            ushort4 hv, lv;
            hv.x = bf16_rn(r0); lv.x = bf16_rn(r0 - bf16f(hv.x));
            hv.y = bf16_rn(r1); lv.y = bf16_rn(r1 - bf16f(hv.y));
            hv.z = bf16_rn(r2); lv.z = bf16_rn(r2 - bf16f(hv.z));
            hv.w = bf16_rn(r3); lv.w = bf16_rn(r3 - bf16f(hv.w));
            *(ushort4*)(dh + base) = hv;
            *(ushort4*)(dl + base) = lv;
        }
    }
}

// ---------------------------------------------------------------------------
// Split-bf16 MFMA flash attention, causal.
// Grid (32 q-tiles [reversed], 32 bh). 256 threads = 4 waves.
// Per block: 64q x 64kv tile; wave w owns q-rows [w*16, w*16+16).
// mfma_f32_16x16x32_bf16; split precision: X = Xhi + Xlo (bf16 pair),
// X*Y = Xhi*Yhi + Xhi*Ylo + Xlo*Yhi (error ~2^-16 rel).
// A-frag: row = lane&15, k = (lane>>4)*8 + j.  B-frag: col = lane&15, same k.
// C/D:    col = lane&15, row = (lane>>4)*4 + reg   [m89/m91 verified].
// K LDS [kv][d], V LDS transposed [d][kv], both with 16B-block XOR swizzle
// (blk ^= row&7) for even bank spread. P (bf16 hi/lo) is per-wave private
// LDS -> no barrier between P write and PV read.
// LDS total 48 KB -> 3 blocks/CU (12 waves).
// ---------------------------------------------------------------------------
__global__ __launch_bounds__(256, 3) void flash_kernel(
    const ushort* __restrict__ qh_g, const ushort* __restrict__ ql_g,
    const ushort* __restrict__ kh_g, const ushort* __restrict__ kl_g,
    const ushort* __restrict__ vh_g, const ushort* __restrict__ vl_g,
    float* __restrict__ attn_ws)
{
    const int bh = blockIdx.y;
    const int qi = (int)(gridDim.x - 1) - (int)blockIdx.x;  // heavy tiles first
    const int t  = threadIdx.x;
    const int w  = t >> 6;        // wave 0..3
    const int l  = t & 63;        // lane
    const int g  = l >> 4;        // lane group 0..3
    const int c  = l & 15;        // lane col 0..15
    const int h  = bh & (NH - 1);
    const int b_idx = bh >> 4;

    __shared__ ushort Kh[64 * 64], Kl[64 * 64];      // [kv][d] swizzled
    __shared__ ushort Vh[64 * 64], Vl[64 * 64];      // [d][kv] swizzled
    __shared__ ushort Ph[4][16 * 64], Pl[4][16 * 64];// per-wave [qrow][kv] swizzled

    // Q A-frags in registers (row = c, k = kc*32 + g*8 + j)
    const long qbase = ((long)bh * S_LEN + qi * 64 + w * 16 + c) * DK;
    s8v qhf[2], qlf[2];
    qhf[0] = *(const s8v*)(qh_g + qbase + g * 8);
    qhf[1] = *(const s8v*)(qh_g + qbase + 32 + g * 8);
    qlf[0] = *(const s8v*)(ql_g + qbase + g * 8);
    qlf[1] = *(const s8v*)(ql_g + qbase + 32 + g * 8);

    f4v o[4];
#pragma unroll
    for (int nt = 0; nt < 4; ++nt) o[nt] = (f4v){0.f, 0.f, 0.f, 0.f};
    float m_[4] = {-INFINITY, -INFINITY, -INFINITY, -INFINITY};
    float l_[4] = {0.f, 0.f, 0.f, 0.f};

    const int sw = c & 7;         // read-side swizzle key (row&7 == c&7 for all reads)
    const int ntiles = qi + 1;

    for (int tile = 0; tile < ntiles; ++tile) {
        __syncthreads();   // prev PV done reading K/V LDS
        {
            const long rb = ((long)bh * S_LEN + tile * 64 + l) * DK;
#pragma unroll
            for (int ib = 0; ib < 2; ++ib) {
                const int b = w + ib * 4;          // 16B block index (d-blocks)
                const int sb = b ^ (l & 7);        // swizzle by kv row
                *(s8v*)&Kh[l * 64 + sb * 8] = *(const s8v*)(kh_g + rb + b * 8);
                *(s8v*)&Kl[l * 64 + sb * 8] = *(const s8v*)(kl_g + rb + b * 8);
                s8v v8h = *(const s8v*)(vh_g + rb + b * 8);
                s8v v8l = *(const s8v*)(vl_g + rb + b * 8);
#pragma unroll
                for (int j = 0; j < 8; ++j) {      // transpose V: [d][kv]
                    const int d = b * 8 + j;
                    const int sc_ = (l >> 3) ^ (d & 7);
                    Vh[d * 64 + sc_ * 8 + (l & 7)] = (ushort)v8h[j];
                    Vl[d * 64 + sc_ * 8 + (l & 7)] = (ushort)v8l[j];
                }
            }
        }
        __syncthreads();

        const bool diag = (tile == qi);
        const int ntmax = diag ? (w + 1) : 4;      // skip fully-masked kv subtiles

        // ---- QK^T (3-pass split), scores in C-frags ----
        f4v sc[4];
#pragma unroll
        for (int nt = 0; nt < 4; ++nt) sc[nt] = (f4v){0.f, 0.f, 0.f, 0.f};
#pragma unroll
        for (int nt = 0; nt < 4; ++nt) {
            if (nt >= ntmax) continue;             // wave-uniform, static indexing kept
            const int kvc = nt * 16 + c;
#pragma unroll
            for (int kc = 0; kc < 2; ++kc) {
                const int blk = (kc * 4 + g) ^ sw;
                s8v khf = *(const s8v*)&Kh[kvc * 64 + blk * 8];
                s8v klf = *(const s8v*)&Kl[kvc * 64 + blk * 8];
                sc[nt] = __builtin_amdgcn_mfma_f32_16x16x32_bf16(qhf[kc], khf, sc[nt], 0, 0, 0);
                sc[nt] = __builtin_amdgcn_mfma_f32_16x16x32_bf16(qhf[kc], klf, sc[nt], 0, 0, 0);
                sc[nt] = __builtin_amdgcn_mfma_f32_16x16x32_bf16(qlf[kc], khf, sc[nt], 0, 0, 0);
            }
        }

        // ---- scale + causal mask ----
        float s_[4][4];
#pragma unroll
        for (int nt = 0; nt < 4; ++nt) {
#pragma unroll
            for (int r = 0; r < 4; ++r) {
                float v = sc[nt][r] * 0.125f;
                bool masked = diag && ((nt > w) || (nt == w && c > 4 * g + r));
                s_[nt][r] = masked ? -INFINITY : v;
            }
        }

        // ---- online softmax (row r = q-row 4g+r; cols across 16 lanes x 4 nt) ----
#pragma unroll
        for (int r = 0; r < 4; ++r) {
            float tmax = fmaxf(fmaxf(s_[0][r], s_[1][r]), fmaxf(s_[2][r], s_[3][r]));
            tmax = fmaxf(tmax, __shfl_xor(tmax, 1, 16));
            tmax = fmaxf(tmax, __shfl_xor(tmax, 2, 16));
            tmax = fmaxf(tmax, __shfl_xor(tmax, 4, 16));
            tmax = fmaxf(tmax, __shfl_xor(tmax, 8, 16));
            const float mnew = fmaxf(m_[r], tmax);
            const float corr = __expf(m_[r] - mnew);   // first tile: exp(-inf)=0
            const int row = 4 * g + r;
            float psum = 0.f;
#pragma unroll
            for (int nt = 0; nt < 4; ++nt) {
                const float p = __expf(s_[nt][r] - mnew);
                psum += p;
                const ushort hh = bf16_rn(p);
                const ushort ll = bf16_rn(p - bf16f(hh));
                const int col = nt * 16 + c;
                const int idx = row * 64 + (((col >> 3) ^ (row & 7)) << 3) + (col & 7);
                Ph[w][idx] = hh;
                Pl[w][idx] = ll;
            }
            psum += __shfl_xor(psum, 1, 16);
            psum += __shfl_xor(psum, 2, 16);
            psum += __shfl_xor(psum, 4, 16);
            psum += __shfl_xor(psum, 8, 16);
            l_[r] = l_[r] * corr + psum;
            m_[r] = mnew;
#pragma unroll
            for (int nt = 0; nt < 4; ++nt) o[nt][r] *= corr;
        }

        // ---- PV (3-pass split). P is wave-private: lgkmcnt ordering suffices. ----
        const int kcmax = (diag && w < 2) ? 1 : 2;  // kv 32..63 all-zero P for w<2
#pragma unroll
        for (int kc = 0; kc < 2; ++kc) {
            if (kc >= kcmax) continue;
            const int blk = (kc * 4 + g) ^ sw;
            s8v pah = *(const s8v*)&Ph[w][c * 64 + blk * 8];
            s8v pal = *(const s8v*)&Pl[w][c * 64 + blk * 8];
#pragma unroll
            for (int nt = 0; nt < 4; ++nt) {
                const int dcol = nt * 16 + c;
                s8v vhf = *(const s8v*)&Vh[dcol * 64 + blk * 8];
                s8v vlf = *(const s8v*)&Vl[dcol * 64 + blk * 8];
                o[nt] = __builtin_amdgcn_mfma_f32_16x16x32_bf16(pah, vhf, o[nt], 0, 0, 0);
                o[nt] = __builtin_amdgcn_mfma_f32_16x16x32_bf16(pah, vlf, o[nt], 0, 0, 0);
                o[nt] = __builtin_amdgcn_mfma_f32_16x16x32_bf16(pal, vhf, o[nt], 0, 0, 0);
            }
        }
    }

    // ---- epilogue: normalize, store attn_ws[b][s][h*64+d] ----
#pragma unroll
    for (int r = 0; r < 4; ++r) {
        const float inv = 1.0f / l_[r];
        const int qrow_g = qi * 64 + w * 16 + 4 * g + r;
        float* op = attn_ws + ((long)b_idx * S_LEN + qrow_g) * DM + h * DK;
#pragma unroll
        for (int nt = 0; nt < 4; ++nt)
            op[nt * 16 + c] = o[nt][r] * inv;
    }
}

// ---------------------------------------------------------------------------
extern "C" void kernel_launch(void* const* d_in, const int* in_sizes, int n_in,
                              void* d_out, int out_size, void* d_ws, size_t ws_size,
                              hipStream_t stream) {
    const float* x   = (const float*)d_in[0];
    const float* Wq  = (const float*)d_in[1];
    const float* bq  = (const float*)d_in[2];
    const float* Wk  = (const float*)d_in[3];
    const float* bk  = (const float*)d_in[4];
    const float* Wv  = (const float*)d_in[5];
    const float* bv  = (const float*)d_in[6];
    const float* Wo  = (const float*)d_in[7];
    const float* bo  = (const float*)d_in[8];
    const int* tokpos = (const int*)d_in[9];
    float* out = (float*)d_out;

    char* wsb = (char*)d_ws;
    const long NE = 4194304;                     // 2*16*2048*64 elems per array
    ushort* qh = (ushort*)wsb;                   // 6 x 8MB bf16 hi/lo arrays
    ushort* ql = qh + NE;
    ushort* kh = ql + NE;
    ushort* kl = kh + NE;
    ushort* vh = kl + NE;
    ushort* vl = vh + NE;
    float* attn_ws  = (float*)(wsb + 48u * 1024 * 1024);   // 16MB
    float* rope_tab = (float*)(wsb + 64u * 1024 * 1024);   // 512KB

    rope_table_kernel<<<(S_LEN * 32 + 255) / 256, 256, 0, stream>>>(rope_tab);

    gemm_kernel<0><<<dim3(64, 16, 3), 256, 0, stream>>>(
        x, Wq, Wk, Wv, bq, bk, bv, rope_tab, tokpos,
        qh, ql, kh, kl, vh, vl, nullptr);

    flash_kernel<<<dim3(32, 32), 256, 0, stream>>>(qh, ql, kh, kl, vh, vl, attn_ws);

    gemm_kernel<1><<<dim3(64, 16, 1), 256, 0, stream>>>(
        attn_ws, Wo, nullptr, nullptr, bo, nullptr, nullptr,
        rope_tab, tokpos,
        nullptr, nullptr, nullptr, nullptr, nullptr, nullptr, out);
}

// Round 4
// 542.291 us; speedup vs baseline: 2.8885x; 1.5575x over previous
//
#include <hip/hip_runtime.h>
#include <math.h>

#define S_LEN 2048
#define DM 1024
#define NH 16
#define DK 64

typedef short s8v __attribute__((ext_vector_type(8)));   // 8 bf16 (A/B frag, 4 VGPR)
typedef float f4v __attribute__((ext_vector_type(4)));   // 4 f32  (C/D frag)

__device__ inline ushort bf16_rn(float v) {
    unsigned u = __float_as_uint(v);
    u += 0x7FFFu + ((u >> 16) & 1u);
    return (ushort)(u >> 16);
}
__device__ inline float bf16f(ushort h) { return __uint_as_float(((unsigned)h) << 16); }

// split 8 fp32 into bf16 hi + lo (residual) vectors
__device__ inline void split8(float4 a, float4 b, s8v& hi, s8v& lo) {
    float f[8] = {a.x, a.y, a.z, a.w, b.x, b.y, b.z, b.w};
#pragma unroll
    for (int i = 0; i < 8; ++i) {
        ushort h = bf16_rn(f[i]);
        hi[i] = (short)h;
        lo[i] = (short)bf16_rn(f[i] - bf16f(h));
    }
}

// ---------------------------------------------------------------------------
// RoPE cos/sin table: tab[p][i] = {cos(p*invf_i), sin(p*invf_i)}, i in [0,32)
// ---------------------------------------------------------------------------
__global__ __launch_bounds__(256) void rope_table_kernel(float* __restrict__ tab) {
    int idx = blockIdx.x * 256 + threadIdx.x;
    if (idx >= S_LEN * 32) return;
    int p = idx >> 5, i = idx & 31;
    float invf = powf(10000.0f, -(float)(2 * i) / 64.0f);
    float ang = (float)p * invf;
    tab[idx * 2 + 0] = cosf(ang);
    tab[idx * 2 + 1] = sinf(ang);
}

// ---------------------------------------------------------------------------
// Split-bf16 MFMA GEMM: C[m,e] = sum_k A[m,k]*W[e,k] + bias (+RoPE epilogue).
// A,W are fp32 in global; converted to bf16 hi/lo during LDS staging
// (identical global bytes, no extra workspace). 3-pass split:
// A*W ~= Ah*Wh + Ah*Wl + Al*Wh  (rel err ~2^-16).
// Tile: BM=128, BN=64, BK=64. 256 threads = 4 waves (2x2), wave tile 64x32
// = 4 m-frags x 2 n-frags of 16x16x32 MFMA. LDS 48 KB, XOR-swizzled 16B
// blocks (blk ^ row&7) -> conflict-free b128 reads (flash-proven pattern).
// Register-prefetch next K-chunk during MFMA compute.
// MODE 0: QKV proj (z = which), epilogue RoPE + split-store [b,h,s,dk].
// MODE 1: out proj, epilogue fp32 store to d_out.
// ---------------------------------------------------------------------------
template <int MODE>
__global__ __launch_bounds__(256, 2) void mfma_gemm(
    const float* __restrict__ A,
    const float* __restrict__ W0, const float* __restrict__ W1, const float* __restrict__ W2,
    const float* __restrict__ b0, const float* __restrict__ b1, const float* __restrict__ b2,
    const float* __restrict__ rope_tab, const int* __restrict__ tokpos,
    ushort* __restrict__ qh, ushort* __restrict__ ql,
    ushort* __restrict__ kh, ushort* __restrict__ kl,
    ushort* __restrict__ vh, ushort* __restrict__ vl,
    float* __restrict__ out)
{
    const int m0 = blockIdx.x * 128;
    const int n0 = blockIdx.y * 64;
    const int which = (MODE == 0) ? blockIdx.z : 0;
    const float* W    = (which == 0) ? W0 : (which == 1) ? W1 : W2;
    const float* bias = (which == 0) ? b0 : (which == 1) ? b1 : b2;

    __shared__ ushort Ah[128 * 64], Al[128 * 64];   // [row][k] swizzled
    __shared__ ushort Bh[64 * 64],  Bl[64 * 64];

    const int t = threadIdx.x;
    const int w = t >> 6, l = t & 63, g = l >> 4, c = l & 15;
    const int wm = w >> 1, wn = w & 1;

    const int rA = t >> 2;          // staging row 0..63 (A also row+64)
    const int bA = t & 3;           // staging col-blocks bA, bA+4

    f4v acc[4][2];
#pragma unroll
    for (int i = 0; i < 4; ++i)
#pragma unroll
        for (int j = 0; j < 2; ++j) acc[i][j] = (f4v){0.f, 0.f, 0.f, 0.f};

    const float* Ap0 = A + (long)(m0 + rA) * DM + bA * 8;
    const float* Ap1 = A + (long)(m0 + rA + 64) * DM + bA * 8;
    const float* Wp  = W + (long)(n0 + rA) * DM + bA * 8;

    float4 pa[8], pb[4];
    // prologue: prefetch chunk 0
    pa[0] = *(const float4*)(Ap0 + 0);  pa[1] = *(const float4*)(Ap0 + 4);
    pa[2] = *(const float4*)(Ap0 + 32); pa[3] = *(const float4*)(Ap0 + 36);
    pa[4] = *(const float4*)(Ap1 + 0);  pa[5] = *(const float4*)(Ap1 + 4);
    pa[6] = *(const float4*)(Ap1 + 32); pa[7] = *(const float4*)(Ap1 + 36);
    pb[0] = *(const float4*)(Wp + 0);   pb[1] = *(const float4*)(Wp + 4);
    pb[2] = *(const float4*)(Wp + 32);  pb[3] = *(const float4*)(Wp + 36);

    const int sb0 = (bA     ^ (rA & 7)) * 8;
    const int sb1 = ((bA+4) ^ (rA & 7)) * 8;

    for (int ch = 0; ch < 16; ++ch) {
        __syncthreads();   // previous compute done reading LDS
        {
            s8v hi, lo;
            split8(pa[0], pa[1], hi, lo);
            *(s8v*)&Ah[rA*64 + sb0] = hi;       *(s8v*)&Al[rA*64 + sb0] = lo;
            split8(pa[2], pa[3], hi, lo);
            *(s8v*)&Ah[rA*64 + sb1] = hi;       *(s8v*)&Al[rA*64 + sb1] = lo;
            split8(pa[4], pa[5], hi, lo);
            *(s8v*)&Ah[(rA+64)*64 + sb0] = hi;  *(s8v*)&Al[(rA+64)*64 + sb0] = lo;
            split8(pa[6], pa[7], hi, lo);
            *(s8v*)&Ah[(rA+64)*64 + sb1] = hi;  *(s8v*)&Al[(rA+64)*64 + sb1] = lo;
            split8(pb[0], pb[1], hi, lo);
            *(s8v*)&Bh[rA*64 + sb0] = hi;       *(s8v*)&Bl[rA*64 + sb0] = lo;
            split8(pb[2], pb[3], hi, lo);
            *(s8v*)&Bh[rA*64 + sb1] = hi;       *(s8v*)&Bl[rA*64 + sb1] = lo;
        }
        __syncthreads();

        if (ch + 1 < 16) {          // prefetch next chunk; hides under MFMA
            const int k0 = (ch + 1) * 64;
            pa[0] = *(const float4*)(Ap0 + k0 + 0);  pa[1] = *(const float4*)(Ap0 + k0 + 4);
            pa[2] = *(const float4*)(Ap0 + k0 + 32); pa[3] = *(const float4*)(Ap0 + k0 + 36);
            pa[4] = *(const float4*)(Ap1 + k0 + 0);  pa[5] = *(const float4*)(Ap1 + k0 + 4);
            pa[6] = *(const float4*)(Ap1 + k0 + 32); pa[7] = *(const float4*)(Ap1 + k0 + 36);
            pb[0] = *(const float4*)(Wp + k0 + 0);   pb[1] = *(const float4*)(Wp + k0 + 4);
            pb[2] = *(const float4*)(Wp + k0 + 32);  pb[3] = *(const float4*)(Wp + k0 + 36);
        }

#pragma unroll
        for (int kc = 0; kc < 2; ++kc) {
            const int blk = ((kc*4 + g) ^ (c & 7)) * 8;
            s8v afh[4], afl[4], bfh[2], bfl[2];
#pragma unroll
            for (int mf = 0; mf < 4; ++mf) {
                const int row = wm*64 + mf*16 + c;
                afh[mf] = *(const s8v*)&Ah[row*64 + blk];
                afl[mf] = *(const s8v*)&Al[row*64 + blk];
            }
#pragma unroll
            for (int nf = 0; nf < 2; ++nf) {
                const int row = wn*32 + nf*16 + c;
                bfh[nf] = *(const s8v*)&Bh[row*64 + blk];
                bfl[nf] = *(const s8v*)&Bl[row*64 + blk];
            }
#pragma unroll
            for (int mf = 0; mf < 4; ++mf)
#pragma unroll
                for (int nf = 0; nf < 2; ++nf) {
                    acc[mf][nf] = __builtin_amdgcn_mfma_f32_16x16x32_bf16(afh[mf], bfh[nf], acc[mf][nf], 0, 0, 0);
                    acc[mf][nf] = __builtin_amdgcn_mfma_f32_16x16x32_bf16(afh[mf], bfl[nf], acc[mf][nf], 0, 0, 0);
                    acc[mf][nf] = __builtin_amdgcn_mfma_f32_16x16x32_bf16(afl[mf], bfh[nf], acc[mf][nf], 0, 0, 0);
                }
        }
    }

    // ---- epilogue ----
#pragma unroll
    for (int nf = 0; nf < 2; ++nf) {
        const int ecol = n0 + wn*32 + nf*16 + c;
        const float bv = bias[ecol];
        if (MODE == 1) {
#pragma unroll
            for (int mf = 0; mf < 4; ++mf)
#pragma unroll
                for (int r = 0; r < 4; ++r) {
                    const int m = m0 + wm*64 + mf*16 + 4*g + r;
                    out[(long)m * DM + ecol] = acc[mf][nf][r] + bv;
                }
        } else {
            const int hH = ecol >> 6, dk = ecol & 63, fi = dk >> 1;
            ushort* dh = (which == 0) ? qh : (which == 1) ? kh : vh;
            ushort* dl = (which == 0) ? ql : (which == 1) ? kl : vl;
#pragma unroll
            for (int mf = 0; mf < 4; ++mf)
#pragma unroll
                for (int r = 0; r < 4; ++r) {
                    const int m = m0 + wm*64 + mf*16 + 4*g + r;
                    const float val = acc[mf][nf][r] + bv;
                    const float par = __shfl_xor(val, 1);   // pair partner (col^1)
                    float vr;
                    if (which == 2) {
                        vr = val;                           // V: no RoPE
                    } else {
                        const int pos = tokpos[m];
                        const float2 cs = ((const float2*)rope_tab)[pos * 32 + fi];
                        vr = (c & 1) ? fmaf(par, cs.y, val * cs.x)     // odd:  x1*sin + x2*cos
                                     : fmaf(val, cs.x, -par * cs.y);   // even: x1*cos - x2*sin
                    }
                    const ushort hh = bf16_rn(vr);
                    const ushort ll = bf16_rn(vr - bf16f(hh));
                    const long base = ((long)((m >> 11) * NH + hH) * S_LEN + (m & (S_LEN - 1))) * DK + dk;
                    dh[base] = hh;
                    dl[base] = ll;
                }
        }
    }
}

// ---------------------------------------------------------------------------
// Split-bf16 MFMA flash attention, causal (round-3 structure + register
// prefetch of next K/V tile + lane-paired b32 V-transpose commit).
// Grid (32 q-tiles [reversed], 32 bh). 256 threads = 4 waves.
// ---------------------------------------------------------------------------
__global__ __launch_bounds__(256, 3) void flash_kernel(
    const ushort* __restrict__ qh_g, const ushort* __restrict__ ql_g,
    const ushort* __restrict__ kh_g, const ushort* __restrict__ kl_g,
    const ushort* __restrict__ vh_g, const ushort* __restrict__ vl_g,
    float* __restrict__ attn_ws)
{
    const int bh = blockIdx.y;
    const int qi = (int)(gridDim.x - 1) - (int)blockIdx.x;  // heavy tiles first
    const int t  = threadIdx.x;
    const int w  = t >> 6;
    const int l  = t & 63;
    const int g  = l >> 4;
    const int c  = l & 15;
    const int h  = bh & (NH - 1);
    const int b_idx = bh >> 4;

    __shared__ ushort Kh[64 * 64], Kl[64 * 64];      // [kv][d] swizzled
    __shared__ ushort Vh[64 * 64], Vl[64 * 64];      // [d][kv] swizzled
    __shared__ ushort Ph[4][16 * 64], Pl[4][16 * 64];// per-wave [qrow][kv] swizzled

    const long qbase = ((long)bh * S_LEN + qi * 64 + w * 16 + c) * DK;
    s8v qhf[2], qlf[2];
    qhf[0] = *(const s8v*)(qh_g + qbase + g * 8);
    qhf[1] = *(const s8v*)(qh_g + qbase + 32 + g * 8);
    qlf[0] = *(const s8v*)(ql_g + qbase + g * 8);
    qlf[1] = *(const s8v*)(ql_g + qbase + 32 + g * 8);

    f4v o[4];
#pragma unroll
    for (int nt = 0; nt < 4; ++nt) o[nt] = (f4v){0.f, 0.f, 0.f, 0.f};
    float m_[4] = {-INFINITY, -INFINITY, -INFINITY, -INFINITY};
    float l_[4] = {0.f, 0.f, 0.f, 0.f};

    const int sw = c & 7;
    const int ntiles = qi + 1;

    // register prefetch of tile 0
    s8v pkh[2], pkl[2], pvh[2], pvl[2];
    {
        const long rb = ((long)bh * S_LEN + l) * DK;
#pragma unroll
        for (int ib = 0; ib < 2; ++ib) {
            const int b = w + ib * 4;
            pkh[ib] = *(const s8v*)(kh_g + rb + b * 8);
            pkl[ib] = *(const s8v*)(kl_g + rb + b * 8);
            pvh[ib] = *(const s8v*)(vh_g + rb + b * 8);
            pvl[ib] = *(const s8v*)(vl_g + rb + b * 8);
        }
    }

    for (int tile = 0; tile < ntiles; ++tile) {
        __syncthreads();   // prev compute done reading K/V LDS

        // ---- commit prefetched K (b128) and V (transposed, b32 lane-pairs) ----
#pragma unroll
        for (int ib = 0; ib < 2; ++ib) {
            const int b = w + ib * 4;
            const int sb = b ^ (l & 7);
            *(s8v*)&Kh[l * 64 + sb * 8] = pkh[ib];
            *(s8v*)&Kl[l * 64 + sb * 8] = pkl[ib];

            uint4 uh = *(uint4*)&pvh[ib];
            uint4 ul = *(uint4*)&pvl[ib];
            uint4 ph_, pl_;
            ph_.x = (uint)__shfl_xor((int)uh.x, 1); ph_.y = (uint)__shfl_xor((int)uh.y, 1);
            ph_.z = (uint)__shfl_xor((int)uh.z, 1); ph_.w = (uint)__shfl_xor((int)uh.w, 1);
            pl_.x = (uint)__shfl_xor((int)ul.x, 1); pl_.y = (uint)__shfl_xor((int)ul.y, 1);
            pl_.z = (uint)__shfl_xor((int)ul.z, 1); pl_.w = (uint)__shfl_xor((int)ul.w, 1);
            const int colp = l & ~1;
            const int odd  = l & 1;
#pragma unroll
            for (int j = 0; j < 4; ++j) {
                const ushort oj   = ((const ushort*)&uh)[j];
                const ushort oj4  = ((const ushort*)&uh)[j + 4];
                const ushort pj   = ((const ushort*)&ph_)[j];
                const ushort pj4  = ((const ushort*)&ph_)[j + 4];
                const ushort loj  = ((const ushort*)&ul)[j];
                const ushort loj4 = ((const ushort*)&ul)[j + 4];
                const ushort plj  = ((const ushort*)&pl_)[j];
                const ushort plj4 = ((const ushort*)&pl_)[j + 4];
                const int d   = b * 8 + (odd ? 4 + j : j);
                const uint hv = odd ? ((uint)pj4  | ((uint)oj4  << 16))
                                    : ((uint)oj   | ((uint)pj   << 16));
                const uint lv = odd ? ((uint)plj4 | ((uint)loj4 << 16))
                                    : ((uint)loj  | ((uint)plj  << 16));
                const int sc2 = (colp >> 3) ^ (d & 7);
                *(uint*)&Vh[d * 64 + sc2 * 8 + (colp & 7)] = hv;
                *(uint*)&Vl[d * 64 + sc2 * 8 + (colp & 7)] = lv;
            }
        }
        __syncthreads();

        // ---- prefetch next tile (hides under compute) ----
        if (tile + 1 < ntiles) {
            const long rb = ((long)bh * S_LEN + (tile + 1) * 64 + l) * DK;
#pragma unroll
            for (int ib = 0; ib < 2; ++ib) {
                const int b = w + ib * 4;
                pkh[ib] = *(const s8v*)(kh_g + rb + b * 8);
                pkl[ib] = *(const s8v*)(kl_g + rb + b * 8);
                pvh[ib] = *(const s8v*)(vh_g + rb + b * 8);
                pvl[ib] = *(const s8v*)(vl_g + rb + b * 8);
            }
        }

        const bool diag = (tile == qi);
        const int ntmax = diag ? (w + 1) : 4;

        // ---- QK^T (3-pass split) ----
        f4v sc[4];
#pragma unroll
        for (int nt = 0; nt < 4; ++nt) sc[nt] = (f4v){0.f, 0.f, 0.f, 0.f};
#pragma unroll
        for (int nt = 0; nt < 4; ++nt) {
            if (nt >= ntmax) continue;
            const int kvc = nt * 16 + c;
#pragma unroll
            for (int kc = 0; kc < 2; ++kc) {
                const int blk = (kc * 4 + g) ^ sw;
                s8v khf = *(const s8v*)&Kh[kvc * 64 + blk * 8];
                s8v klf = *(const s8v*)&Kl[kvc * 64 + blk * 8];
                sc[nt] = __builtin_amdgcn_mfma_f32_16x16x32_bf16(qhf[kc], khf, sc[nt], 0, 0, 0);
                sc[nt] = __builtin_amdgcn_mfma_f32_16x16x32_bf16(qhf[kc], klf, sc[nt], 0, 0, 0);
                sc[nt] = __builtin_amdgcn_mfma_f32_16x16x32_bf16(qlf[kc], khf, sc[nt], 0, 0, 0);
            }
        }

        // ---- scale + causal mask ----
        float s_[4][4];
#pragma unroll
        for (int nt = 0; nt < 4; ++nt) {
#pragma unroll
            for (int r = 0; r < 4; ++r) {
                float v = sc[nt][r] * 0.125f;
                bool masked = diag && ((nt > w) || (nt == w && c > 4 * g + r));
                s_[nt][r] = masked ? -INFINITY : v;
            }
        }

        // ---- online softmax ----
#pragma unroll
        for (int r = 0; r < 4; ++r) {
            float tmax = fmaxf(fmaxf(s_[0][r], s_[1][r]), fmaxf(s_[2][r], s_[3][r]));
            tmax = fmaxf(tmax, __shfl_xor(tmax, 1, 16));
            tmax = fmaxf(tmax, __shfl_xor(tmax, 2, 16));
            tmax = fmaxf(tmax, __shfl_xor(tmax, 4, 16));
            tmax = fmaxf(tmax, __shfl_xor(tmax, 8, 16));
            const float mnew = fmaxf(m_[r], tmax);
            const float corr = __expf(m_[r] - mnew);
            const int row = 4 * g + r;
            float psum = 0.f;
#pragma unroll
            for (int nt = 0; nt < 4; ++nt) {
                const float p = __expf(s_[nt][r] - mnew);
                psum += p;
                const ushort hh = bf16_rn(p);
                const ushort ll = bf16_rn(p - bf16f(hh));
                const int col = nt * 16 + c;
                const int idx = row * 64 + (((col >> 3) ^ (row & 7)) << 3) + (col & 7);
                Ph[w][idx] = hh;
                Pl[w][idx] = ll;
            }
            psum += __shfl_xor(psum, 1, 16);
            psum += __shfl_xor(psum, 2, 16);
            psum += __shfl_xor(psum, 4, 16);
            psum += __shfl_xor(psum, 8, 16);
            l_[r] = l_[r] * corr + psum;
            m_[r] = mnew;
#pragma unroll
            for (int nt = 0; nt < 4; ++nt) o[nt][r] *= corr;
        }

        // ---- PV (3-pass split), wave-private P ----
        const int kcmax = (diag && w < 2) ? 1 : 2;
#pragma unroll
        for (int kc = 0; kc < 2; ++kc) {
            if (kc >= kcmax) continue;
            const int blk = (kc * 4 + g) ^ sw;
            s8v pah = *(const s8v*)&Ph[w][c * 64 + blk * 8];
            s8v pal = *(const s8v*)&Pl[w][c * 64 + blk * 8];
#pragma unroll
            for (int nt = 0; nt < 4; ++nt) {
                const int dcol = nt * 16 + c;
                s8v vhf = *(const s8v*)&Vh[dcol * 64 + blk * 8];
                s8v vlf = *(const s8v*)&Vl[dcol * 64 + blk * 8];
                o[nt] = __builtin_amdgcn_mfma_f32_16x16x32_bf16(pah, vhf, o[nt], 0, 0, 0);
                o[nt] = __builtin_amdgcn_mfma_f32_16x16x32_bf16(pah, vlf, o[nt], 0, 0, 0);
                o[nt] = __builtin_amdgcn_mfma_f32_16x16x32_bf16(pal, vhf, o[nt], 0, 0, 0);
            }
        }
    }

    // ---- epilogue: normalize, store attn_ws[b][s][h*64+d] (fp32) ----
#pragma unroll
    for (int r = 0; r < 4; ++r) {
        const float inv = 1.0f / l_[r];
        const int qrow_g = qi * 64 + w * 16 + 4 * g + r;
        float* op = attn_ws + ((long)b_idx * S_LEN + qrow_g) * DM + h * DK;
#pragma unroll
        for (int nt = 0; nt < 4; ++nt)
            op[nt * 16 + c] = o[nt][r] * inv;
    }
}

// ---------------------------------------------------------------------------
extern "C" void kernel_launch(void* const* d_in, const int* in_sizes, int n_in,
                              void* d_out, int out_size, void* d_ws, size_t ws_size,
                              hipStream_t stream) {
    const float* x   = (const float*)d_in[0];
    const float* Wq  = (const float*)d_in[1];
    const float* bq  = (const float*)d_in[2];
    const float* Wk  = (const float*)d_in[3];
    const float* bk  = (const float*)d_in[4];
    const float* Wv  = (const float*)d_in[5];
    const float* bv  = (const float*)d_in[6];
    const float* Wo  = (const float*)d_in[7];
    const float* bo  = (const float*)d_in[8];
    const int* tokpos = (const int*)d_in[9];
    float* out = (float*)d_out;

    char* wsb = (char*)d_ws;
    const long NE = 4194304;                     // 2*16*2048*64 elems per array
    ushort* qh = (ushort*)wsb;                   // 6 x 8MB bf16 hi/lo arrays
    ushort* ql = qh + NE;
    ushort* kh = ql + NE;
    ushort* kl = kh + NE;
    ushort* vh = kl + NE;
    ushort* vl = vh + NE;
    float* attn_ws  = (float*)(wsb + 48u * 1024 * 1024);   // 16MB fp32
    float* rope_tab = (float*)(wsb + 64u * 1024 * 1024);   // 512KB

    rope_table_kernel<<<(S_LEN * 32 + 255) / 256, 256, 0, stream>>>(rope_tab);

    // QKV projections (split-bf16 MFMA) + bias + RoPE + hi/lo scatter
    mfma_gemm<0><<<dim3(32, 16, 3), 256, 0, stream>>>(
        x, Wq, Wk, Wv, bq, bk, bv, rope_tab, tokpos,
        qh, ql, kh, kl, vh, vl, nullptr);

    // causal flash attention
    flash_kernel<<<dim3(32, 32), 256, 0, stream>>>(qh, ql, kh, kl, vh, vl, attn_ws);

    // output projection (split-bf16 MFMA) + bias -> d_out
    mfma_gemm<1><<<dim3(32, 16, 1), 256, 0, stream>>>(
        attn_ws, Wo, nullptr, nullptr, bo, nullptr, nullptr,
        rope_tab, tokpos,
        nullptr, nullptr, nullptr, nullptr, nullptr, nullptr, out);
}

// Round 5
// 389.572 us; speedup vs baseline: 4.0208x; 1.3920x over previous
//
#include <hip/hip_runtime.h>
#include <math.h>

#define S_LEN 2048
#define DM 1024
#define NH 16
#define DK 64

typedef short s8v __attribute__((ext_vector_type(8)));   // 8 bf16 (A/B frag, 4 VGPR)
typedef float f4v __attribute__((ext_vector_type(4)));   // 4 f32  (C/D frag)

__device__ inline ushort bf16_rn(float v) {
    unsigned u = __float_as_uint(v);
    u += 0x7FFFu + ((u >> 16) & 1u);
    return (ushort)(u >> 16);
}
__device__ inline float bf16f(ushort h) { return __uint_as_float(((unsigned)h) << 16); }

// ---------------------------------------------------------------------------
// Pre-split fp32 -> bf16 hi + lo residual for x and the 4 weight matrices.
// ---------------------------------------------------------------------------
__global__ __launch_bounds__(256) void convert_kernel(
    const float* __restrict__ x,
    const float* __restrict__ Wq, const float* __restrict__ Wk,
    const float* __restrict__ Wv, const float* __restrict__ Wo,
    ushort* __restrict__ xh, ushort* __restrict__ xl,
    ushort* __restrict__ wh, ushort* __restrict__ wl)
{
    long idx = (long)blockIdx.x * 256 + threadIdx.x;    // 2M float4 groups
    const float4* src;
    ushort* dh; ushort* dl; long off;
    if (idx < 1048576) {                                 // x: 4M elems
        src = (const float4*)x; off = idx; dh = xh; dl = xl;
    } else {
        long wi = idx - 1048576;
        int which = (int)(wi >> 18);                     // 262144 groups per W
        const float* wp = which == 0 ? Wq : which == 1 ? Wk : which == 2 ? Wv : Wo;
        src = (const float4*)wp; off = wi & 262143;
        dh = wh + (long)which * 1048576;
        dl = wl + (long)which * 1048576;
    }
    float4 v = src[off];
    ushort4 hv, lv;
    hv.x = bf16_rn(v.x); lv.x = bf16_rn(v.x - bf16f(hv.x));
    hv.y = bf16_rn(v.y); lv.y = bf16_rn(v.y - bf16f(hv.y));
    hv.z = bf16_rn(v.z); lv.z = bf16_rn(v.z - bf16f(hv.z));
    hv.w = bf16_rn(v.w); lv.w = bf16_rn(v.w - bf16f(hv.w));
    ((ushort4*)dh)[off] = hv;
    ((ushort4*)dl)[off] = lv;
}

// ---------------------------------------------------------------------------
// RoPE cos/sin table
// ---------------------------------------------------------------------------
__global__ __launch_bounds__(256) void rope_table_kernel(float* __restrict__ tab) {
    int idx = blockIdx.x * 256 + threadIdx.x;
    if (idx >= S_LEN * 32) return;
    int p = idx >> 5, i = idx & 31;
    float invf = powf(10000.0f, -(float)(2 * i) / 64.0f);
    float ang = (float)p * invf;
    tab[idx * 2 + 0] = cosf(ang);
    tab[idx * 2 + 1] = sinf(ang);
}

// ---------------------------------------------------------------------------
// Split-bf16 MFMA GEMM on pre-split inputs (no conversion VALU in staging).
// C[m,e] = sum_k A[m,k]*W[e,k] + bias; 3-pass split Ah*Wh + Ah*Wl + Al*Wh.
// BM=128, BN=64, BK=64; 4 waves (2x2); wave tile 64x32 (4 m-frag x 2 n-frag).
// LDS 48KB, XOR-swizzled 16B blocks; register-prefetched staging.
// MODE 0: QKV proj (z-> which), epilogue RoPE + hi/lo scatter [b,h,s,dk].
// MODE 1: out proj (which=3 -> Wo), epilogue fp32 store.
// ---------------------------------------------------------------------------
template <int MODE>
__global__ __launch_bounds__(256, 2) void mfma_gemm(
    const ushort* __restrict__ Ah_g, const ushort* __restrict__ Al_g,
    const ushort* __restrict__ Wh_g, const ushort* __restrict__ Wl_g,
    const float* __restrict__ b0, const float* __restrict__ b1, const float* __restrict__ b2,
    const float* __restrict__ rope_tab, const int* __restrict__ tokpos,
    ushort* __restrict__ qh, ushort* __restrict__ ql,
    ushort* __restrict__ kh, ushort* __restrict__ kl,
    ushort* __restrict__ vh, ushort* __restrict__ vl,
    float* __restrict__ out)
{
    const int m0 = blockIdx.x * 128;
    const int n0 = blockIdx.y * 64;
    const int which = (MODE == 0) ? blockIdx.z : 0;
    const ushort* WhP = Wh_g + (long)(MODE == 0 ? which : 3) * 1048576;
    const ushort* WlP = Wl_g + (long)(MODE == 0 ? which : 3) * 1048576;
    const float* bias = (which == 0) ? b0 : (which == 1) ? b1 : b2;

    __shared__ ushort Ah[128 * 64], Al[128 * 64];   // 16KB each
    __shared__ ushort Bh[64 * 64],  Bl[64 * 64];    // 8KB each

    const int t = threadIdx.x;
    const int w = t >> 6, l = t & 63, g = l >> 4, c = l & 15;
    const int wm = w >> 1, wn = w & 1;

    const int rA2 = t >> 1;            // A staging row 0..127
    const int kh0 = (t & 1) * 32;      // A k-half
    const int rW  = t >> 2;            // W staging row 0..63
    const int kq0 = (t & 3) * 16;      // W k-quarter

    f4v acc[4][2];
#pragma unroll
    for (int i = 0; i < 4; ++i)
#pragma unroll
        for (int j = 0; j < 2; ++j) acc[i][j] = (f4v){0.f, 0.f, 0.f, 0.f};

    const ushort* ApH = Ah_g + (long)(m0 + rA2) * DM + kh0;
    const ushort* ApL = Al_g + (long)(m0 + rA2) * DM + kh0;
    const ushort* WpH = WhP + (long)(n0 + rW) * DM + kq0;
    const ushort* WpL = WlP + (long)(n0 + rW) * DM + kq0;

    s8v pah[4], pal[4], pwh[2], pwl[2];
#pragma unroll
    for (int q = 0; q < 4; ++q) {
        pah[q] = *(const s8v*)(ApH + q * 8);
        pal[q] = *(const s8v*)(ApL + q * 8);
    }
#pragma unroll
    for (int q = 0; q < 2; ++q) {
        pwh[q] = *(const s8v*)(WpH + q * 8);
        pwl[q] = *(const s8v*)(WpL + q * 8);
    }

    for (int ch = 0; ch < 16; ++ch) {
        __syncthreads();
#pragma unroll
        for (int q = 0; q < 4; ++q) {
            const int b = (kh0 >> 3) + q;
            const int sb = (b ^ (rA2 & 7)) * 8;
            *(s8v*)&Ah[rA2 * 64 + sb] = pah[q];
            *(s8v*)&Al[rA2 * 64 + sb] = pal[q];
        }
#pragma unroll
        for (int q = 0; q < 2; ++q) {
            const int b = (kq0 >> 3) + q;
            const int sb = (b ^ (rW & 7)) * 8;
            *(s8v*)&Bh[rW * 64 + sb] = pwh[q];
            *(s8v*)&Bl[rW * 64 + sb] = pwl[q];
        }
        __syncthreads();

        if (ch + 1 < 16) {
            const int k0 = (ch + 1) * 64;
#pragma unroll
            for (int q = 0; q < 4; ++q) {
                pah[q] = *(const s8v*)(ApH + k0 + q * 8);
                pal[q] = *(const s8v*)(ApL + k0 + q * 8);
            }
#pragma unroll
            for (int q = 0; q < 2; ++q) {
                pwh[q] = *(const s8v*)(WpH + k0 + q * 8);
                pwl[q] = *(const s8v*)(WpL + k0 + q * 8);
            }
        }

#pragma unroll
        for (int kc = 0; kc < 2; ++kc) {
            const int blk = ((kc * 4 + g) ^ (c & 7)) * 8;
            s8v afh[4], afl[4], bfh[2], bfl[2];
#pragma unroll
            for (int mf = 0; mf < 4; ++mf) {
                const int row = wm * 64 + mf * 16 + c;
                afh[mf] = *(const s8v*)&Ah[row * 64 + blk];
                afl[mf] = *(const s8v*)&Al[row * 64 + blk];
            }
#pragma unroll
            for (int nf = 0; nf < 2; ++nf) {
                const int row = wn * 32 + nf * 16 + c;
                bfh[nf] = *(const s8v*)&Bh[row * 64 + blk];
                bfl[nf] = *(const s8v*)&Bl[row * 64 + blk];
            }
#pragma unroll
            for (int mf = 0; mf < 4; ++mf)
#pragma unroll
                for (int nf = 0; nf < 2; ++nf) {
                    acc[mf][nf] = __builtin_amdgcn_mfma_f32_16x16x32_bf16(afh[mf], bfh[nf], acc[mf][nf], 0, 0, 0);
                    acc[mf][nf] = __builtin_amdgcn_mfma_f32_16x16x32_bf16(afh[mf], bfl[nf], acc[mf][nf], 0, 0, 0);
                    acc[mf][nf] = __builtin_amdgcn_mfma_f32_16x16x32_bf16(afl[mf], bfh[nf], acc[mf][nf], 0, 0, 0);
                }
        }
    }

    // ---- epilogue ----
#pragma unroll
    for (int nf = 0; nf < 2; ++nf) {
        const int ecol = n0 + wn * 32 + nf * 16 + c;
        const float bv = bias[ecol];
        if (MODE == 1) {
#pragma unroll
            for (int mf = 0; mf < 4; ++mf)
#pragma unroll
                for (int r = 0; r < 4; ++r) {
                    const int m = m0 + wm * 64 + mf * 16 + 4 * g + r;
                    out[(long)m * DM + ecol] = acc[mf][nf][r] + bv;
                }
        } else {
            const int hH = ecol >> 6, dk = ecol & 63, fi = dk >> 1;
            ushort* dh = (which == 0) ? qh : (which == 1) ? kh : vh;
            ushort* dl = (which == 0) ? ql : (which == 1) ? kl : vl;
#pragma unroll
            for (int mf = 0; mf < 4; ++mf)
#pragma unroll
                for (int r = 0; r < 4; ++r) {
                    const int m = m0 + wm * 64 + mf * 16 + 4 * g + r;
                    const float val = acc[mf][nf][r] + bv;
                    const float par = __shfl_xor(val, 1);
                    float vr;
                    if (which == 2) {
                        vr = val;
                    } else {
                        const int pos = tokpos[m];
                        const float2 cs = ((const float2*)rope_tab)[pos * 32 + fi];
                        vr = (c & 1) ? fmaf(par, cs.y, val * cs.x)
                                     : fmaf(val, cs.x, -par * cs.y);
                    }
                    const ushort hh = bf16_rn(vr);
                    const ushort ll = bf16_rn(vr - bf16f(hh));
                    const long base = ((long)((m >> 11) * NH + hH) * S_LEN + (m & (S_LEN - 1))) * DK + dk;
                    dh[base] = hh;
                    dl[base] = ll;
                }
        }
    }
}

// ---------------------------------------------------------------------------
// Split-bf16 MFMA flash attention, causal, SWAPPED QK^T.
// Grid (16 q-blocks [reversed], 32 bh) = 512 blocks = 2/CU, all co-resident.
// Block: 128q x 64kv; 4 waves, wave w owns q-rows [w*32, w*32+32) (2 q-frags).
// S^T = K*Q^T via mfma(A=K-frag, B=Q-frag): lane holds S^T[kv=16nt+4g+r][q=c]
// -> softmax row q=c is 16 in-lane values + 2 shfl_xor (vs 32 shfls before).
// P packed to bf16 hi/lo u32 pairs in-register, 16 ds_write_b64 per tile
// (wave-private, no barrier), read back as b128 A-frags for PV.
// K/V LDS XOR-swizzled; V transposed at commit via lane-pair shfl.
// O rows live as q=4g+r -> corr/inv redistributed by 4 shfls per qf.
// LDS = 32KB (K/V) + 32KB (P) = 64KB -> 2 blocks/CU.
// ---------------------------------------------------------------------------
__global__ __launch_bounds__(256, 2) void flash_kernel(
    const ushort* __restrict__ qh_g, const ushort* __restrict__ ql_g,
    const ushort* __restrict__ kh_g, const ushort* __restrict__ kl_g,
    const ushort* __restrict__ vh_g, const ushort* __restrict__ vl_g,
    ushort* __restrict__ ah_g, ushort* __restrict__ al_g)
{
    const int bh = blockIdx.y;
    const int qb = 15 - (int)blockIdx.x;      // heavy blocks first
    const int t = threadIdx.x;
    const int w = t >> 6, l = t & 63, g = l >> 4, c = l & 15;
    const int h = bh & (NH - 1), b_idx = bh >> 4;
    const int q0w = qb * 128 + w * 32;

    __shared__ ushort Kh[64 * 64], Kl[64 * 64];   // [kv][d] swizzled, 8KB each
    __shared__ ushort Vh[64 * 64], Vl[64 * 64];   // [d][kv] swizzled
    __shared__ uint P_[8192];                      // [wave][qf][q16][hl][32 u32]
    uint* Pw = P_ + (w * 2) * 1024;

    // Q B-frags (col=q=c, k=d)
    s8v qhf[2][2], qlf[2][2];
#pragma unroll
    for (int qf = 0; qf < 2; ++qf)
#pragma unroll
        for (int kc = 0; kc < 2; ++kc) {
            const long base = ((long)bh * S_LEN + q0w + qf * 16 + c) * DK + kc * 32 + g * 8;
            qhf[qf][kc] = *(const s8v*)(qh_g + base);
            qlf[qf][kc] = *(const s8v*)(ql_g + base);
        }

    f4v o[2][4];
#pragma unroll
    for (int qf = 0; qf < 2; ++qf)
#pragma unroll
        for (int nt = 0; nt < 4; ++nt) o[qf][nt] = (f4v){0.f, 0.f, 0.f, 0.f};
    float m_[2] = {-INFINITY, -INFINITY};
    float l_[2] = {0.f, 0.f};

    const int ntiles = 2 * qb + 2;

    // register prefetch of tile 0
    s8v pkh[2], pkl[2], pvh[2], pvl[2];
    {
        const long rb = ((long)bh * S_LEN + l) * DK;
#pragma unroll
        for (int ib = 0; ib < 2; ++ib) {
            const int b = w + ib * 4;
            pkh[ib] = *(const s8v*)(kh_g + rb + b * 8);
            pkl[ib] = *(const s8v*)(kl_g + rb + b * 8);
            pvh[ib] = *(const s8v*)(vh_g + rb + b * 8);
            pvl[ib] = *(const s8v*)(vl_g + rb + b * 8);
        }
    }

    for (int tile = 0; tile < ntiles; ++tile) {
        __syncthreads();

        // ---- commit K (b128) + V transposed (lane-pair b32) ----
#pragma unroll
        for (int ib = 0; ib < 2; ++ib) {
            const int b = w + ib * 4;
            const int sb = b ^ (l & 7);
            *(s8v*)&Kh[l * 64 + sb * 8] = pkh[ib];
            *(s8v*)&Kl[l * 64 + sb * 8] = pkl[ib];

            uint4 uh = *(uint4*)&pvh[ib];
            uint4 ul = *(uint4*)&pvl[ib];
            uint4 ph_, pl_;
            ph_.x = (uint)__shfl_xor((int)uh.x, 1); ph_.y = (uint)__shfl_xor((int)uh.y, 1);
            ph_.z = (uint)__shfl_xor((int)uh.z, 1); ph_.w = (uint)__shfl_xor((int)uh.w, 1);
            pl_.x = (uint)__shfl_xor((int)ul.x, 1); pl_.y = (uint)__shfl_xor((int)ul.y, 1);
            pl_.z = (uint)__shfl_xor((int)ul.z, 1); pl_.w = (uint)__shfl_xor((int)ul.w, 1);
            const int colp = l & ~1;
            const int odd  = l & 1;
#pragma unroll
            for (int j = 0; j < 4; ++j) {
                const ushort oj   = ((const ushort*)&uh)[j];
                const ushort oj4  = ((const ushort*)&uh)[j + 4];
                const ushort pj   = ((const ushort*)&ph_)[j];
                const ushort pj4  = ((const ushort*)&ph_)[j + 4];
                const ushort loj  = ((const ushort*)&ul)[j];
                const ushort loj4 = ((const ushort*)&ul)[j + 4];
                const ushort plj  = ((const ushort*)&pl_)[j];
                const ushort plj4 = ((const ushort*)&pl_)[j + 4];
                const int d   = b * 8 + (odd ? 4 + j : j);
                const uint hv = odd ? ((uint)pj4  | ((uint)oj4  << 16))
                                    : ((uint)oj   | ((uint)pj   << 16));
                const uint lv = odd ? ((uint)plj4 | ((uint)loj4 << 16))
                                    : ((uint)loj  | ((uint)plj  << 16));
                const int sc2 = (colp >> 3) ^ (d & 7);
                *(uint*)&Vh[d * 64 + sc2 * 8 + (colp & 7)] = hv;
                *(uint*)&Vl[d * 64 + sc2 * 8 + (colp & 7)] = lv;
            }
        }
        __syncthreads();

        // ---- prefetch next tile ----
        if (tile + 1 < ntiles) {
            const long rb = ((long)bh * S_LEN + (tile + 1) * 64 + l) * DK;
#pragma unroll
            for (int ib = 0; ib < 2; ++ib) {
                const int b = w + ib * 4;
                pkh[ib] = *(const s8v*)(kh_g + rb + b * 8);
                pkl[ib] = *(const s8v*)(kl_g + rb + b * 8);
                pvh[ib] = *(const s8v*)(vh_g + rb + b * 8);
                pvl[ib] = *(const s8v*)(vl_g + rb + b * 8);
            }
        }

        const int kvbase = tile * 64;
        int nt_hi[2];
#pragma unroll
        for (int qf = 0; qf < 2; ++qf) {
            const int lim = q0w + qf * 16 + 15 - kvbase;
            int v = lim < 0 ? 0 : (lim >> 4) + 1;
            nt_hi[qf] = v > 4 ? 4 : v;
        }
        const bool dz = (kvbase + 63) > q0w;

        // ---- S^T = K * Q^T (3-pass split); K-frag shared across qf ----
        f4v sc[2][4];
#pragma unroll
        for (int qf = 0; qf < 2; ++qf)
#pragma unroll
            for (int nt = 0; nt < 4; ++nt) sc[qf][nt] = (f4v){0.f, 0.f, 0.f, 0.f};
#pragma unroll
        for (int nt = 0; nt < 4; ++nt) {
            if (nt >= nt_hi[1]) continue;
            const int kvl = nt * 16 + c;
#pragma unroll
            for (int kc = 0; kc < 2; ++kc) {
                const int blk = ((kc * 4 + g) ^ (c & 7)) * 8;
                s8v kfh = *(const s8v*)&Kh[kvl * 64 + blk];
                s8v kfl = *(const s8v*)&Kl[kvl * 64 + blk];
#pragma unroll
                for (int qf = 0; qf < 2; ++qf) {
                    if (nt >= nt_hi[qf]) continue;
                    sc[qf][nt] = __builtin_amdgcn_mfma_f32_16x16x32_bf16(kfh, qhf[qf][kc], sc[qf][nt], 0, 0, 0);
                    sc[qf][nt] = __builtin_amdgcn_mfma_f32_16x16x32_bf16(kfh, qlf[qf][kc], sc[qf][nt], 0, 0, 0);
                    sc[qf][nt] = __builtin_amdgcn_mfma_f32_16x16x32_bf16(kfl, qhf[qf][kc], sc[qf][nt], 0, 0, 0);
                }
            }
        }

        // ---- softmax (row q=c in-lane) + packed P write + O rescale ----
#pragma unroll
        for (int qf = 0; qf < 2; ++qf) {
            if (nt_hi[qf] == 0) continue;
            float s_[4][4];
#pragma unroll
            for (int nt = 0; nt < 4; ++nt)
#pragma unroll
                for (int r = 0; r < 4; ++r) {
                    const float v = sc[qf][nt][r] * 0.125f;
                    const bool bad = (nt >= nt_hi[qf]) ||
                        (dz && (kvbase + 16 * nt + 4 * g + r > q0w + qf * 16 + c));
                    s_[nt][r] = bad ? -INFINITY : v;
                }
            float tm = -INFINITY;
#pragma unroll
            for (int nt = 0; nt < 4; ++nt)
#pragma unroll
                for (int r = 0; r < 4; ++r) tm = fmaxf(tm, s_[nt][r]);
            tm = fmaxf(tm, __shfl_xor(tm, 16));
            tm = fmaxf(tm, __shfl_xor(tm, 32));
            const float mnew = fmaxf(m_[qf], tm);
            const float corr = __expf(m_[qf] - mnew);
            uint* Pq = Pw + qf * 1024 + c * 64;
            float psum = 0.f;
#pragma unroll
            for (int nt = 0; nt < 4; ++nt) {
                const float p0 = __expf(s_[nt][0] - mnew);
                const float p1 = __expf(s_[nt][1] - mnew);
                const float p2 = __expf(s_[nt][2] - mnew);
                const float p3 = __expf(s_[nt][3] - mnew);
                psum += (p0 + p1) + (p2 + p3);
                const ushort h0 = bf16_rn(p0), h1 = bf16_rn(p1);
                const ushort h2 = bf16_rn(p2), h3 = bf16_rn(p3);
                const ushort e0 = bf16_rn(p0 - bf16f(h0)), e1 = bf16_rn(p1 - bf16f(h1));
                const ushort e2 = bf16_rn(p2 - bf16f(h2)), e3 = bf16_rn(p3 - bf16f(h3));
                const int u0 = ((2 * nt + (g >> 1)) ^ (c & 7)) * 4 + 2 * (g & 1);
                uint2 hw; hw.x = (uint)h0 | ((uint)h1 << 16); hw.y = (uint)h2 | ((uint)h3 << 16);
                uint2 lw; lw.x = (uint)e0 | ((uint)e1 << 16); lw.y = (uint)e2 | ((uint)e3 << 16);
                *(uint2*)(Pq + u0) = hw;
                *(uint2*)(Pq + 32 + u0) = lw;
            }
            psum += __shfl_xor(psum, 16);
            psum += __shfl_xor(psum, 32);
            l_[qf] = l_[qf] * corr + psum;
            m_[qf] = mnew;
            // redistribute corr to O-row holders (row q = 4g+r)
            float cD0 = __shfl(corr, (l & 48) + 4 * g + 0);
            float cD1 = __shfl(corr, (l & 48) + 4 * g + 1);
            float cD2 = __shfl(corr, (l & 48) + 4 * g + 2);
            float cD3 = __shfl(corr, (l & 48) + 4 * g + 3);
#pragma unroll
            for (int nt = 0; nt < 4; ++nt) {
                o[qf][nt][0] *= cD0; o[qf][nt][1] *= cD1;
                o[qf][nt][2] *= cD2; o[qf][nt][3] *= cD3;
            }
        }

        // ---- PV (3-pass split); V-frags shared across qf ----
#pragma unroll
        for (int kc = 0; kc < 2; ++kc) {
            if (nt_hi[1] <= kc * 2) continue;
            const bool q0go = nt_hi[0] > kc * 2;
            const int pswz = ((4 * kc + g) ^ (c & 7)) * 4;
            s8v pa1h = *(const s8v*)(Pw + 1024 + c * 64 + pswz);
            s8v pa1l = *(const s8v*)(Pw + 1024 + c * 64 + 32 + pswz);
            s8v pa0h, pa0l;
            if (q0go) {
                pa0h = *(const s8v*)(Pw + c * 64 + pswz);
                pa0l = *(const s8v*)(Pw + c * 64 + 32 + pswz);
            }
#pragma unroll
            for (int nt = 0; nt < 4; ++nt) {
                const int dcol = nt * 16 + c;
                const int vblk = ((kc * 4 + g) ^ (c & 7)) * 8;
                s8v vfh = *(const s8v*)&Vh[dcol * 64 + vblk];
                s8v vfl = *(const s8v*)&Vl[dcol * 64 + vblk];
                o[1][nt] = __builtin_amdgcn_mfma_f32_16x16x32_bf16(pa1h, vfh, o[1][nt], 0, 0, 0);
                o[1][nt] = __builtin_amdgcn_mfma_f32_16x16x32_bf16(pa1h, vfl, o[1][nt], 0, 0, 0);
                o[1][nt] = __builtin_amdgcn_mfma_f32_16x16x32_bf16(pa1l, vfh, o[1][nt], 0, 0, 0);
                if (q0go) {
                    o[0][nt] = __builtin_amdgcn_mfma_f32_16x16x32_bf16(pa0h, vfh, o[0][nt], 0, 0, 0);
                    o[0][nt] = __builtin_amdgcn_mfma_f32_16x16x32_bf16(pa0h, vfl, o[0][nt], 0, 0, 0);
                    o[0][nt] = __builtin_amdgcn_mfma_f32_16x16x32_bf16(pa0l, vfh, o[0][nt], 0, 0, 0);
                }
            }
        }
    }

    // ---- epilogue: normalize (inv redistributed), split-store bf16 hi/lo ----
#pragma unroll
    for (int qf = 0; qf < 2; ++qf) {
        const float inv = 1.0f / l_[qf];
        float iD0 = __shfl(inv, (l & 48) + 4 * g + 0);
        float iD1 = __shfl(inv, (l & 48) + 4 * g + 1);
        float iD2 = __shfl(inv, (l & 48) + 4 * g + 2);
        float iD3 = __shfl(inv, (l & 48) + 4 * g + 3);
#pragma unroll
        for (int nt = 0; nt < 4; ++nt) {
            float v0 = o[qf][nt][0] * iD0;
            float v1 = o[qf][nt][1] * iD1;
            float v2 = o[qf][nt][2] * iD2;
            float v3 = o[qf][nt][3] * iD3;
            const long row0 = (long)b_idx * S_LEN + q0w + qf * 16 + 4 * g;
            const long col = h * DK + nt * 16 + c;
            float vv[4] = {v0, v1, v2, v3};
#pragma unroll
            for (int r = 0; r < 4; ++r) {
                const ushort hh = bf16_rn(vv[r]);
                const ushort ll = bf16_rn(vv[r] - bf16f(hh));
                ah_g[(row0 + r) * DM + col] = hh;
                al_g[(row0 + r) * DM + col] = ll;
            }
        }
    }
}

// ---------------------------------------------------------------------------
extern "C" void kernel_launch(void* const* d_in, const int* in_sizes, int n_in,
                              void* d_out, int out_size, void* d_ws, size_t ws_size,
                              hipStream_t stream) {
    const float* x   = (const float*)d_in[0];
    const float* Wq  = (const float*)d_in[1];
    const float* bq  = (const float*)d_in[2];
    const float* Wk  = (const float*)d_in[3];
    const float* bk  = (const float*)d_in[4];
    const float* Wv  = (const float*)d_in[5];
    const float* bv  = (const float*)d_in[6];
    const float* Wo  = (const float*)d_in[7];
    const float* bo  = (const float*)d_in[8];
    const int* tokpos = (const int*)d_in[9];
    float* out = (float*)d_out;

    char* wsb = (char*)d_ws;
    const long NE = 4194304;                       // elems per [b,h,s,dk] array
    ushort* qh = (ushort*)wsb;                     // 6 x 8MB
    ushort* ql = qh + NE;
    ushort* kh = ql + NE;
    ushort* kl = kh + NE;
    ushort* vh = kl + NE;
    ushort* vl = vh + NE;
    ushort* wh = (ushort*)(wsb + 48ll * 1024 * 1024);   // 4 x 1M elems = 8MB
    ushort* wl = (ushort*)(wsb + 56ll * 1024 * 1024);   // 8MB
    ushort* xh = (ushort*)(wsb + 64ll * 1024 * 1024);   // 8MB (reused as attn hi)
    ushort* xl = (ushort*)(wsb + 72ll * 1024 * 1024);   // 8MB (reused as attn lo)
    float* rope_tab = (float*)(wsb + 80ll * 1024 * 1024);

    convert_kernel<<<8192, 256, 0, stream>>>(x, Wq, Wk, Wv, Wo, xh, xl, wh, wl);
    rope_table_kernel<<<256, 256, 0, stream>>>(rope_tab);

    mfma_gemm<0><<<dim3(32, 16, 3), 256, 0, stream>>>(
        xh, xl, wh, wl, bq, bk, bv, rope_tab, tokpos,
        qh, ql, kh, kl, vh, vl, nullptr);

    flash_kernel<<<dim3(16, 32), 256, 0, stream>>>(
        qh, ql, kh, kl, vh, vl, xh, xl);   // attn output aliases xh/xl (x dead)

    mfma_gemm<1><<<dim3(32, 16, 1), 256, 0, stream>>>(
        xh, xl, wh, wl, bo, nullptr, nullptr, rope_tab, tokpos,
        nullptr, nullptr, nullptr, nullptr, nullptr, nullptr, out);
}